// Round 7
// baseline (1096.316 us; speedup 1.0000x reference)
//
#include <hip/hip_runtime.h>
#include <hip/hip_bf16.h>
#include <type_traits>

typedef __hip_bfloat16 bf16;

constexpr int N_  = 250000;
constexpr int E_  = 500000;
constexpr int B_  = 10000;
constexpr int H_  = 128;

typedef short s8v __attribute__((ext_vector_type(8)));   // 8 bf16 in 4 VGPRs
typedef float f4v __attribute__((ext_vector_type(4)));

__device__ __forceinline__ float b2f(bf16 v){ return __bfloat162float(v); }
__device__ __forceinline__ bf16  f2b(float v){ return __float2bfloat16(v); }
__device__ __forceinline__ float to_float(float v){ return v; }
__device__ __forceinline__ float to_float(bf16 v){ return __bfloat162float(v); }
__device__ __forceinline__ float lrelu_f(float v){ return v > 0.f ? v : 0.01f*v; }
__device__ __forceinline__ float sigmoid_f(float x){ return __builtin_amdgcn_rcpf(1.f+__expf(-x)); }
__device__ __forceinline__ float tanh_f(float x){ return 1.f - 2.f*__builtin_amdgcn_rcpf(__expf(2.f*x)+1.f); }
__device__ __forceinline__ float elu_f(float v){ return v > 0.f ? v : __expf(v)-1.f; }
__device__ __forceinline__ unsigned f2b_bits(float f){
  bf16 h=__float2bfloat16(f); unsigned short s; __builtin_memcpy(&s,&h,2); return (unsigned)s;
}
__device__ __forceinline__ void unp8(uint4 v, float* o){
  o[0]=__uint_as_float(v.x<<16); o[1]=__uint_as_float(v.x&0xffff0000u);
  o[2]=__uint_as_float(v.y<<16); o[3]=__uint_as_float(v.y&0xffff0000u);
  o[4]=__uint_as_float(v.z<<16); o[5]=__uint_as_float(v.z&0xffff0000u);
  o[6]=__uint_as_float(v.w<<16); o[7]=__uint_as_float(v.w&0xffff0000u);
}

// ---------------- consolidated fp32->bf16 weight copies (9 segments) -------
struct W2B { const float* s; bf16* d; int rows, ld, ow, cw; };
struct W2B9 { W2B seg[9]; };
__global__ void w2ball_k(W2B9 p){
  W2B g=p.seg[blockIdx.y];
  int i=blockIdx.x*256+threadIdx.x;
  if (i>=g.rows*g.ow) return;
  int r=i/g.ow, k=i-r*g.ow;
  g.d[i] = f2b(k<g.cw ? g.s[(size_t)r*g.ld+k] : 0.f);
}

// ---- fold attention vectors through weight matrices: out = W^T att (x4) ----
__global__ void fold4_k(const float* __restrict__ Wc, const float* __restrict__ cas,
                        const float* __restrict__ cad, const float* __restrict__ Wm,
                        const float* __restrict__ mas, const float* __restrict__ mad,
                        float* __restrict__ w1c, float* __restrict__ w2c,
                        float* __restrict__ wms, float* __restrict__ wdd){
  int k=threadIdx.x; int which=blockIdx.x;
  const float* W  = (which<2)? Wc : Wm;
  const float* at = (which==0)? cas : (which==1)? cad : (which==2)? mas : mad;
  float* out = (which==0)? w1c : (which==1)? w2c : (which==2)? wms : wdd;
  float a=0.f;
  for (int c=0;c<128;c++) a+=at[c]*W[(size_t)c*128+k];
  out[k]=a;
}

// ------- lin1 via MFMA: [N,39] fp32 -> [N,128] bf16, lrelu; fused row-dot --
__global__ __launch_bounds__(256) void lin1_mfma_k(const float* __restrict__ X0, const bf16* __restrict__ Wb,
                            const float* __restrict__ bias, const float* __restrict__ dvec,
                            bf16* __restrict__ Y, float* __restrict__ dout, int M){
  __shared__ __align__(16) bf16 sx[64][72];
  __shared__ float sdot[4][64];
  int wv=threadIdx.x>>6, lane=threadIdx.x&63;
  int n=lane&15, q=lane>>4;
  int c0=wv*32;
  s8v wB[2][2];
  #pragma unroll
  for (int ct=0;ct<2;ct++)
    #pragma unroll
    for (int kk=0;kk<2;kk++)
      wB[ct][kk]=*(const s8v*)(Wb+(size_t)(c0+ct*16+n)*64+kk*32+q*8);
  float bb[2];
  #pragma unroll
  for (int ct=0;ct<2;ct++) bb[ct]=bias[c0+ct*16+n];
  float va[2]={dvec[c0+n], dvec[c0+16+n]};
  for (int i=threadIdx.x;i<64*25;i+=256){ int r=i/25,k=39+(i-(i/25)*25); sx[r][k]=f2b(0.f); }
  for (long r0=(long)blockIdx.x*64; r0<M; r0+=(long)gridDim.x*64){
    __syncthreads();
    for (int f=threadIdx.x; f<64*39; f+=256){
      int r=f/39, k=f-(f/39)*39; long row=r0+r;
      sx[r][k]= f2b(row<M ? X0[row*39+k] : 0.f);
    }
    __syncthreads();
    s8v a[4][2];
    #pragma unroll
    for (int rt=0;rt<4;rt++)
      #pragma unroll
      for (int kk=0;kk<2;kk++)
        a[rt][kk]=*(const s8v*)&sx[rt*16+n][kk*32+q*8];
    f4v acc[4][2];
    #pragma unroll
    for (int rt=0;rt<4;rt++)
      #pragma unroll
      for (int ct=0;ct<2;ct++) acc[rt][ct]=(f4v){0.f,0.f,0.f,0.f};
    #pragma unroll
    for (int kk=0;kk<2;kk++)
      #pragma unroll
      for (int rt=0;rt<4;rt++)
        #pragma unroll
        for (int ct=0;ct<2;ct++)
          acc[rt][ct]=__builtin_amdgcn_mfma_f32_16x16x32_bf16(a[rt][kk],wB[ct][kk],acc[rt][ct],0,0,0);
    #pragma unroll
    for (int rt=0;rt<4;rt++){
      #pragma unroll
      for (int rg=0;rg<4;rg++){
        float y0=lrelu_f(acc[rt][0][rg]+bb[0]);
        float y1=lrelu_f(acc[rt][1][rg]+bb[1]);
        long row=r0+rt*16+q*4+rg;
        if (row<M){
          Y[row*128+c0+n]   =f2b(y0);
          Y[row*128+c0+16+n]=f2b(y1);
        }
        float pa=y0*va[0]+y1*va[1];
        #pragma unroll
        for (int o=1;o<16;o<<=1) pa+=__shfl_xor(pa,o);
        if (n==0) sdot[wv][rt*16+q*4+rg]=pa;
      }
    }
    __syncthreads();
    if (threadIdx.x<64){
      long row=r0+threadIdx.x;
      if (row<M) dout[row]=sdot[0][threadIdx.x]+sdot[1][threadIdx.x]+sdot[2][threadIdx.x]+sdot[3][threadIdx.x];
    }
  }
}

// ---- MFMA linear, weights in registers, grid-stride over 64-row tiles ----
template<int ACT>   // 0 none, 2 elu
__global__ __launch_bounds__(256) void lin_mfma_k(const bf16* __restrict__ X, const bf16* __restrict__ Wb,
                            const float* __restrict__ bias, bf16* __restrict__ Y, int M){
  int wv=threadIdx.x>>6, lane=threadIdx.x&63;
  int n=lane&15, q=lane>>4;
  int c0=wv*32;
  s8v wB[2][4];
  #pragma unroll
  for (int ct=0;ct<2;ct++)
    #pragma unroll
    for (int kk=0;kk<4;kk++)
      wB[ct][kk]=*(const s8v*)(Wb+(size_t)(c0+ct*16+n)*128+kk*32+q*8);
  float bb[2];
  #pragma unroll
  for (int ct=0;ct<2;ct++) bb[ct]=bias? bias[c0+ct*16+n]:0.f;
  for (long r0=(long)blockIdx.x*64; r0<M; r0+=(long)gridDim.x*64){
    s8v a[4][4];
    #pragma unroll
    for (int rt=0;rt<4;rt++){
      long row=r0+rt*16+n; if (row>=M) row=M-1;
      #pragma unroll
      for (int kk=0;kk<4;kk++) a[rt][kk]=*(const s8v*)(X+row*128+kk*32+q*8);
    }
    f4v acc[4][2];
    #pragma unroll
    for (int rt=0;rt<4;rt++)
      #pragma unroll
      for (int ct=0;ct<2;ct++) acc[rt][ct]=(f4v){0.f,0.f,0.f,0.f};
    #pragma unroll
    for (int kk=0;kk<4;kk++)
      #pragma unroll
      for (int rt=0;rt<4;rt++)
        #pragma unroll
        for (int ct=0;ct<2;ct++)
          acc[rt][ct]=__builtin_amdgcn_mfma_f32_16x16x32_bf16(a[rt][kk],wB[ct][kk],acc[rt][ct],0,0,0);
    #pragma unroll
    for (int ct=0;ct<2;ct++){
      int col=c0+ct*16+n;
      #pragma unroll
      for (int rt=0;rt<4;rt++){
        #pragma unroll
        for (int rg=0;rg<4;rg++){
          long row=r0+rt*16+q*4+rg;
          if (row<M){
            float v=acc[rt][ct][rg]+bb[ct];
            if (ACT==2) v=elu_f(v);
            Y[row*128+col]=f2b(v);
          }
        }
      }
    }
  }
}

// ---------------- row dot(s) ----------------
template<typename TY>
__global__ void rowdot_k(const TY* __restrict__ Y, const float* __restrict__ v,
                         float* __restrict__ d, int M){
  __shared__ float sv[128];
  if (threadIdx.x<128) sv[threadIdx.x]=v[threadIdx.x];
  __syncthreads();
  int wv=threadIdx.x>>6, lane=threadIdx.x&63;
  long row=(long)blockIdx.x*4+wv;
  if (row>=M) return;
  float a=to_float(Y[row*128+lane])*sv[lane]+to_float(Y[row*128+64+lane])*sv[64+lane];
  #pragma unroll
  for (int o=32;o;o>>=1) a+=__shfl_xor(a,o);
  if (!lane) d[row]=a;
}

__global__ void rowdot2_k(const bf16* __restrict__ Y, const float* __restrict__ v1,
                          const float* __restrict__ v2, float* __restrict__ d1,
                          float* __restrict__ d2, int M){
  __shared__ float sv1[128], sv2[128];
  if (threadIdx.x<128){ sv1[threadIdx.x]=v1[threadIdx.x]; sv2[threadIdx.x]=v2[threadIdx.x]; }
  __syncthreads();
  int wv=threadIdx.x>>6, lane=threadIdx.x&63;
  long row=(long)blockIdx.x*4+wv;
  if (row>=M) return;
  float x0=b2f(Y[row*128+lane]), x1=b2f(Y[row*128+64+lane]);
  float a=x0*sv1[lane]+x1*sv1[64+lane];
  float b=x0*sv2[lane]+x1*sv2[64+lane];
  #pragma unroll
  for (int o=32;o;o>>=1){ a+=__shfl_xor(a,o); b+=__shfl_xor(b,o); }
  if (!lane){ d1[row]=a; d2[row]=b; }
}

// ---- MFMA fused GRU with folded input-GEMM: A = act(S@Wg^T + gbias) -------
// ACT: 1 relu, 2 elu.  dest = relu(gru(A, X)).  In-place S==dest is safe.
template<int ACT>
__global__ __launch_bounds__(512,1) void gru_gw2_mfma_k(const bf16* __restrict__ S, const bf16* __restrict__ X,
                            const bf16* __restrict__ Wg, const float* __restrict__ gbias,
                            const bf16* __restrict__ Wih, const bf16* __restrict__ Whh,
                            const float* __restrict__ bih, const float* __restrict__ bhh,
                            bf16* __restrict__ dest, int M){
  __shared__ __align__(16) bf16 sS[2][32][136];
  __shared__ __align__(16) bf16 sX[2][32][136];
  __shared__ __align__(16) bf16 sA[32][136];
  int wv=threadIdx.x>>6, lane=threadIdx.x&63;
  int n=lane&15, q=lane>>4;
  int c0=wv*16;
  s8v wI[3][4], wH[3][4], wG[4];
  #pragma unroll
  for (int g=0;g<3;g++)
    #pragma unroll
    for (int kk=0;kk<4;kk++){
      size_t off=((size_t)(g*128+c0+n))*128+kk*32+q*8;
      wI[g][kk]=*(const s8v*)(Wih+off);
      wH[g][kk]=*(const s8v*)(Whh+off);
    }
  #pragma unroll
  for (int kk=0;kk<4;kk++)
    wG[kk]=*(const s8v*)(Wg+(size_t)(c0+n)*128+kk*32+q*8);
  int col=c0+n;
  float bA =gbias[col];
  float br =bih[col]+bhh[col];
  float bz =bih[128+col]+bhh[128+col];
  float bni=bih[256+col], bnh=bhh[256+col];

  int srow=wv*4+q;
  int schunk=n;
  long step=(long)gridDim.x*32;
  long r0=(long)blockIdx.x*32;
  int buf=0;
  {
    long rowg=r0+srow; if (rowg>=M) rowg=M-1;
    uint4 vs=*(const uint4*)(S+rowg*128+schunk*8);
    uint4 vx=*(const uint4*)(X+rowg*128+schunk*8);
    *(uint4*)&sS[0][srow][schunk*8]=vs;
    *(uint4*)&sX[0][srow][schunk*8]=vx;
  }
  __syncthreads();
  for (; r0<M; r0+=step){
    long rn=r0+step;
    uint4 vs, vx; bool pre = rn<M;
    if (pre){
      long rowg=rn+srow; if (rowg>=M) rowg=M-1;
      vs=*(const uint4*)(S+rowg*128+schunk*8);
      vx=*(const uint4*)(X+rowg*128+schunk*8);
    }
    // ---- A = act(S @ Wg^T + gbias) into sA ----
    f4v accA[2];
    accA[0]=(f4v){0.f,0.f,0.f,0.f}; accA[1]=(f4v){0.f,0.f,0.f,0.f};
    #pragma unroll
    for (int kk=0;kk<4;kk++){
      #pragma unroll
      for (int rt=0;rt<2;rt++){
        s8v aS=*(const s8v*)&sS[buf][rt*16+n][(kk*4+q)*8];
        accA[rt]=__builtin_amdgcn_mfma_f32_16x16x32_bf16(aS,wG[kk],accA[rt],0,0,0);
      }
    }
    #pragma unroll
    for (int rt=0;rt<2;rt++)
      #pragma unroll
      for (int rg=0;rg<4;rg++){
        float av=accA[rt][rg]+bA;
        av = (ACT==1)? fmaxf(av,0.f) : elu_f(av);
        sA[rt*16+q*4+rg][col]=f2b(av);
      }
    __syncthreads();
    // ---- GRU from sA (h) and sX[buf] (x) ----
    f4v acc[6][2];
    #pragma unroll
    for (int g=0;g<6;g++)
      #pragma unroll
      for (int rt=0;rt<2;rt++) acc[g][rt]=(f4v){0.f,0.f,0.f,0.f};
    #pragma unroll
    for (int kk=0;kk<4;kk++){
      s8v aA[2], aX[2];
      #pragma unroll
      for (int rt=0;rt<2;rt++){
        aA[rt]=*(const s8v*)&sA[rt*16+n][(kk*4+q)*8];
        aX[rt]=*(const s8v*)&sX[buf][rt*16+n][(kk*4+q)*8];
      }
      #pragma unroll
      for (int g=0;g<3;g++)
        #pragma unroll
        for (int rt=0;rt<2;rt++){
          acc[g  ][rt]=__builtin_amdgcn_mfma_f32_16x16x32_bf16(aA[rt],wI[g][kk],acc[g  ][rt],0,0,0);
          acc[3+g][rt]=__builtin_amdgcn_mfma_f32_16x16x32_bf16(aX[rt],wH[g][kk],acc[3+g][rt],0,0,0);
        }
    }
    float xv[2][4];
    #pragma unroll
    for (int rt=0;rt<2;rt++)
      #pragma unroll
      for (int rg=0;rg<4;rg++)
        xv[rt][rg]=b2f(sX[buf][rt*16+q*4+rg][col]);
    #pragma unroll
    for (int rt=0;rt<2;rt++){
      #pragma unroll
      for (int rg=0;rg<4;rg++){
        long row=r0+rt*16+q*4+rg;
        if (row<M){
          float rgate=sigmoid_f(acc[0][rt][rg]+acc[3][rt][rg]+br);
          float zgate=sigmoid_f(acc[1][rt][rg]+acc[4][rt][rg]+bz);
          float nn=tanh_f(acc[2][rt][rg]+bni + rgate*(acc[5][rt][rg]+bnh));
          float o=(1.f-zgate)*nn + zgate*xv[rt][rg];
          dest[row*128+col]=f2b(fmaxf(o,0.f));
        }
      }
    }
    if (pre){
      *(uint4*)&sS[buf^1][srow][schunk*8]=vs;
      *(uint4*)&sX[buf^1][srow][schunk*8]=vx;
    }
    __syncthreads();
    buf^=1;
  }
}

// ------- scalar fused GRU (molecules, fp32 state) ----
__global__ __launch_bounds__(256) void gru_scalar_k(const float* __restrict__ A, const float* __restrict__ X,
                            const float* __restrict__ Wih, const float* __restrict__ Whh,
                            const float* __restrict__ bih, const float* __restrict__ bhh,
                            float* __restrict__ dest, int M){
  __shared__ unsigned sW[6][32*66];
  __shared__ float sA[8][132], sX[8][132];
  __shared__ float sbi[3][32], sbh[3][32];
  int c0 = blockIdx.y*32;
  for (int i=threadIdx.x; i<6*32*64; i+=256){
    int m=i>>11, r=i&2047, c=r>>6, k2=r&63;
    const float* base = (m<3)? Wih : Whh;
    int g = (m<3)? m : m-3;
    const float* wp = base + ((size_t)(g*128 + c0 + c))*128 + 2*k2;
    sW[m][c*66 + k2] = f2b_bits(wp[0]) | (f2b_bits(wp[1])<<16);
  }
  if (threadIdx.x < 96){
    int g=threadIdx.x>>5, c=threadIdx.x&31;
    sbi[g][c]=bih[g*128+c0+c]; sbh[g][c]=bhh[g*128+c0+c];
  }
  __syncthreads();
  int sub=threadIdx.x>>5, c=threadIdx.x&31;
  for (long r0=(long)blockIdx.x*8; r0<M; r0+=(long)gridDim.x*8){
    __syncthreads();
    for (int i=threadIdx.x;i<8*16;i+=256){
      int rr=i>>4, q=i&15; long row=r0+rr;
      if (row<M){
        *(float4*)&sA[rr][q*8]   = *(const float4*)(A+row*128+q*8);
        *(float4*)&sA[rr][q*8+4] = *(const float4*)(A+row*128+q*8+4);
        *(float4*)&sX[rr][q*8]   = *(const float4*)(X+row*128+q*8);
        *(float4*)&sX[rr][q*8+4] = *(const float4*)(X+row*128+q*8+4);
      } else {
        float4 z=make_float4(0,0,0,0);
        *(float4*)&sA[rr][q*8]=z; *(float4*)&sA[rr][q*8+4]=z;
        *(float4*)&sX[rr][q*8]=z; *(float4*)&sX[rr][q*8+4]=z;
      }
    }
    __syncthreads();
    long row=r0+sub;
    if (row<M){
      const unsigned* wri=&sW[0][c*66]; const unsigned* wzi=&sW[1][c*66]; const unsigned* wni=&sW[2][c*66];
      const unsigned* wrh=&sW[3][c*66]; const unsigned* wzh=&sW[4][c*66]; const unsigned* wnh=&sW[5][c*66];
      const float2* xa=(const float2*)sA[sub]; const float2* xb=(const float2*)sX[sub];
      float ari=0,azi=0,ani=0,arh=0,azh=0,anh=0;
      #pragma unroll 8
      for (int k2=0;k2<64;k2++){
        float2 av=xa[k2], bv=xb[k2];
        unsigned u;
        u=wri[k2]; ari += av.x*__uint_as_float(u<<16) + av.y*__uint_as_float(u&0xffff0000u);
        u=wzi[k2]; azi += av.x*__uint_as_float(u<<16) + av.y*__uint_as_float(u&0xffff0000u);
        u=wni[k2]; ani += av.x*__uint_as_float(u<<16) + av.y*__uint_as_float(u&0xffff0000u);
        u=wrh[k2]; arh += bv.x*__uint_as_float(u<<16) + bv.y*__uint_as_float(u&0xffff0000u);
        u=wzh[k2]; azh += bv.x*__uint_as_float(u<<16) + bv.y*__uint_as_float(u&0xffff0000u);
        u=wnh[k2]; anh += bv.x*__uint_as_float(u<<16) + bv.y*__uint_as_float(u&0xffff0000u);
      }
      float rg = sigmoid_f(ari+arh+sbi[0][c]+sbh[0][c]);
      float zg = sigmoid_f(azi+azh+sbi[1][c]+sbh[1][c]);
      float nn = tanh_f(ani+sbi[2][c] + rg*(anh+sbh[2][c]));
      float xv = sX[sub][c0+c];
      float o  = (1.f-zg)*nn + zg*xv;
      dest[row*128+c0+c] = fmaxf(o,0.f);
    }
  }
}

// ---- GATE edge logits: 32 lanes/edge, 1-deep prefetch (best measured) ----
__global__ __launch_bounds__(256) void gate_edge_logits_k(const bf16* __restrict__ u, const float* __restrict__ ea,
                                   const float* __restrict__ gW1, const float* __restrict__ att_l,
                                   const float* __restrict__ ddst, const int* __restrict__ src,
                                   const int* __restrict__ dst, const int* __restrict__ epos,
                                   float* __restrict__ elog, int E){
  int wv=threadIdx.x>>6, lane=threadIdx.x&63;
  int t=lane&31;               // 32 lanes per edge, 4 cols each
  float w[10][4];
  #pragma unroll
  for (int k=0;k<10;k++)
    #pragma unroll
    for (int j=0;j<4;j++)
      w[k][j]=gW1[(size_t)(t*4+j)*138 + 128 + k];
  float al[4];
  #pragma unroll
  for (int j=0;j<4;j++) al[j]=att_l[t*4+j];

  long stride=(long)gridDim.x*8;
  long e=(long)blockIdx.x*8 + wv*2 + (lane>>5);
  if (e>=E) return;
  int sj=src[e];
  uint2 uv=*(const uint2*)(u+(size_t)sj*128+t*4);
  const float2* er=(const float2*)(ea+(size_t)e*10);
  float2 c0=er[0],c1=er[1],c2=er[2],c3=er[3],c4=er[4];
  float dv=ddst[dst[e]];
  int ep=epos[e];
  while (true){
    long en=e+stride; bool has=en<E;
    uint2 uvn=make_uint2(0,0);
    float2 d0={0,0},d1={0,0},d2={0,0},d3={0,0},d4={0,0};
    float dvn=0.f; int epn=0;
    if (has){
      int sjn=src[en];
      uvn=*(const uint2*)(u+(size_t)sjn*128+t*4);
      const float2* ern=(const float2*)(ea+(size_t)en*10);
      d0=ern[0];d1=ern[1];d2=ern[2];d3=ern[3];d4=ern[4];
      dvn=ddst[dst[en]];
      epn=epos[en];
    }
    float uf[4];
    uf[0]=__uint_as_float(uv.x<<16); uf[1]=__uint_as_float(uv.x&0xffff0000u);
    uf[2]=__uint_as_float(uv.y<<16); uf[3]=__uint_as_float(uv.y&0xffff0000u);
    float acc=0.f;
    #pragma unroll
    for (int j=0;j<4;j++){
      float v=uf[j];
      v+=c0.x*w[0][j]; v+=c0.y*w[1][j];
      v+=c1.x*w[2][j]; v+=c1.y*w[3][j];
      v+=c2.x*w[4][j]; v+=c2.y*w[5][j];
      v+=c3.x*w[6][j]; v+=c3.y*w[7][j];
      v+=c4.x*w[8][j]; v+=c4.y*w[9][j];
      acc+=lrelu_f(v)*al[j];
    }
    #pragma unroll
    for (int o=16;o;o>>=1) acc+=__shfl_xor(acc,o);
    if (t==0) elog[ep]=lrelu_f(acc+dv);
    if (!has) break;
    e=en; uv=uvn; c0=d0;c1=d1;c2=d2;c3=d3;c4=d4; dv=dvn; ep=epn;
  }
}

// ------- per-node softmax + weighted sum; 8 lanes/node, 8 nodes/wave -------
template<int ACT>   // 0 none
__global__ void node_gather_k(const float* __restrict__ elog, const int* __restrict__ srcp,
                              const int* __restrict__ ptr, const bf16* __restrict__ V,
                              const float* __restrict__ bias, bf16* __restrict__ S, int M){
  int wv=threadIdx.x>>6, lane=threadIdx.x&63;
  int g=lane>>3, t=lane&7;
  int node=blockIdx.x*32 + wv*8 + g;
  if (node>=M) return;
  int p0=ptr[node], p1=ptr[node+1];
  float m=-INFINITY;
  for (int p=p0+t;p<p1;p+=8) m=fmaxf(m,elog[p]);
  #pragma unroll
  for (int o=4;o;o>>=1) m=fmaxf(m,__shfl_xor(m,o));
  float ssum=0.f;
  float acc[16]={0,0,0,0,0,0,0,0,0,0,0,0,0,0,0,0};
  if (p0<p1){
    float lg=elog[p0];
    const uint4* vp=(const uint4*)(V+(size_t)srcp[p0]*128+t*16);
    uint4 va=vp[0], vb=vp[1];
    for (int p=p0+1;p<p1;p++){
      float lgn=elog[p];
      const uint4* vpn=(const uint4*)(V+(size_t)srcp[p]*128+t*16);
      uint4 van=vpn[0], vbn=vpn[1];
      float e=__expf(lg-m); ssum+=e;
      float xf[8]; unp8(va,xf);
      #pragma unroll
      for (int j=0;j<8;j++) acc[j]+=e*xf[j];
      unp8(vb,xf);
      #pragma unroll
      for (int j=0;j<8;j++) acc[8+j]+=e*xf[j];
      lg=lgn; va=van; vb=vbn;
    }
    float e=__expf(lg-m); ssum+=e;
    float xf[8]; unp8(va,xf);
    #pragma unroll
    for (int j=0;j<8;j++) acc[j]+=e*xf[j];
    unp8(vb,xf);
    #pragma unroll
    for (int j=0;j<8;j++) acc[8+j]+=e*xf[j];
  }
  float inv=1.f/(ssum+1e-16f);
  #pragma unroll
  for (int j=0;j<16;j++) acc[j]*=inv;
  uint4 o1,o2;
  o1.x=f2b_bits(acc[0])|(f2b_bits(acc[1])<<16);
  o1.y=f2b_bits(acc[2])|(f2b_bits(acc[3])<<16);
  o1.z=f2b_bits(acc[4])|(f2b_bits(acc[5])<<16);
  o1.w=f2b_bits(acc[6])|(f2b_bits(acc[7])<<16);
  o2.x=f2b_bits(acc[8])|(f2b_bits(acc[9])<<16);
  o2.y=f2b_bits(acc[10])|(f2b_bits(acc[11])<<16);
  o2.z=f2b_bits(acc[12])|(f2b_bits(acc[13])<<16);
  o2.w=f2b_bits(acc[14])|(f2b_bits(acc[15])<<16);
  *(uint4*)(S+(size_t)node*128+t*16)=o1;
  *(uint4*)(S+(size_t)node*128+t*16+8)=o2;
}

// ---- conv GAT aggregation (raw): 8 lanes/node, online softmax, inline logit;
// ---- aggregates RAW x rows (convW GEMM is folded into GRU2) ----
__global__ __launch_bounds__(256) void conv_gather_raw_k(const float* __restrict__ dsrc, const float* __restrict__ ddst,
    const int* __restrict__ ptr, const int* __restrict__ srcp,
    const bf16* __restrict__ V, bf16* __restrict__ S, int M){
  int wv=threadIdx.x>>6, lane=threadIdx.x&63;
  int g=lane>>3, t=lane&7;
  int node=blockIdx.x*32 + wv*8 + g;
  if (node>=M) return;
  int p0=ptr[node], p1=ptr[node+1];
  float dvn=ddst[node];
  float m=-INFINITY, s=0.f;
  float acc[16]={0,0,0,0,0,0,0,0,0,0,0,0,0,0,0,0};
  if (p0<p1){
    int sj=srcp[p0];
    float ls=dsrc[sj];
    const uint4* vp=(const uint4*)(V+(size_t)sj*128+t*16);
    uint4 va=vp[0], vb=vp[1];
    for (int p=p0+1;p<p1;p++){
      int sjn=srcp[p];
      float lsn=dsrc[sjn];
      const uint4* vpn=(const uint4*)(V+(size_t)sjn*128+t*16);
      uint4 van=vpn[0], vbn=vpn[1];
      float l=lrelu_f(ls+dvn);
      float mn=fmaxf(m,l), sc=__expf(m-mn), ee=__expf(l-mn);
      float xf[8]; unp8(va,xf);
      s=s*sc+ee;
      #pragma unroll
      for (int j=0;j<8;j++) acc[j]=acc[j]*sc+ee*xf[j];
      unp8(vb,xf);
      #pragma unroll
      for (int j=0;j<8;j++) acc[8+j]=acc[8+j]*sc+ee*xf[j];
      m=mn; ls=lsn; va=van; vb=vbn;
    }
    float l=lrelu_f(ls+dvn);
    float mn=fmaxf(m,l), sc=__expf(m-mn), ee=__expf(l-mn);
    float xf[8]; unp8(va,xf);
    s=s*sc+ee;
    #pragma unroll
    for (int j=0;j<8;j++) acc[j]=acc[j]*sc+ee*xf[j];
    unp8(vb,xf);
    #pragma unroll
    for (int j=0;j<8;j++) acc[8+j]=acc[8+j]*sc+ee*xf[j];
  }
  float inv=1.f/(s+1e-16f);
  #pragma unroll
  for (int j=0;j<16;j++) acc[j]*=inv;
  uint4 o1,o2;
  o1.x=f2b_bits(acc[0])|(f2b_bits(acc[1])<<16);
  o1.y=f2b_bits(acc[2])|(f2b_bits(acc[3])<<16);
  o1.z=f2b_bits(acc[4])|(f2b_bits(acc[5])<<16);
  o1.w=f2b_bits(acc[6])|(f2b_bits(acc[7])<<16);
  o2.x=f2b_bits(acc[8])|(f2b_bits(acc[9])<<16);
  o2.y=f2b_bits(acc[10])|(f2b_bits(acc[11])<<16);
  o2.z=f2b_bits(acc[12])|(f2b_bits(acc[13])<<16);
  o2.w=f2b_bits(acc[14])|(f2b_bits(acc[15])<<16);
  *(uint4*)(S+(size_t)node*128+t*16)=o1;
  *(uint4*)(S+(size_t)node*128+t*16+8)=o2;
}

// ---------------- molecule kernels ----------------
__global__ void mol_ptr_k(const int* __restrict__ batch, int* __restrict__ mptr, int n, int Bn){
  int b=blockIdx.x*256+threadIdx.x; if (b>Bn) return;
  if (b==Bn){ mptr[Bn]=n; return; }
  int lo=0, hi=n;
  while (lo<hi){ int mid=(lo+hi)>>1; if (batch[mid]<b) lo=mid+1; else hi=mid; }
  mptr[b]=lo;
}

__global__ void mol_sum_k(const bf16* __restrict__ x, const int* __restrict__ mptr,
                          float* __restrict__ out, int Bn){
  int wv=threadIdx.x>>6, lane=threadIdx.x&63;
  int b=blockIdx.x*4+wv; if (b>=Bn) return;
  int p0=mptr[b], p1=mptr[b+1];
  float a0=0.f,a1=0.f;
  for (int i=p0;i<p1;i++){ a0+=b2f(x[(size_t)i*128+lane]); a1+=b2f(x[(size_t)i*128+64+lane]); }
  out[(size_t)b*128+lane]=fmaxf(a0,0.f); out[(size_t)b*128+64+lane]=fmaxf(a1,0.f);
}

// ==== mol fused raw: dd=out[b].wdd inline; online softmax over atoms; ====
// ==== aggregates RAW x rows -> fp32 P (molW GEMM deferred to mol_lin) ====
__global__ __launch_bounds__(256) void mol_fused_raw_k(const float* __restrict__ dsrc, const int* __restrict__ mptr,
    const bf16* __restrict__ x, const float* __restrict__ wdd, const float* __restrict__ outc,
    float* __restrict__ P, int Bn){
  int wv=threadIdx.x>>6, lane=threadIdx.x&63;
  long b=(long)blockIdx.x*4+wv; if (b>=Bn) return;
  int p0=mptr[b], p1=mptr[b+1];
  float dd=outc[(size_t)b*128+lane]*wdd[lane]+outc[(size_t)b*128+64+lane]*wdd[64+lane];
  #pragma unroll
  for (int o=32;o;o>>=1) dd+=__shfl_xor(dd,o);
  float m=-INFINITY, s=0.f, a0=0.f, a1=0.f;
  for (int i=p0;i<p1;i++){
    float a=lrelu_f(dsrc[i]+dd);
    float x0=b2f(x[(size_t)i*128+lane]), x1=b2f(x[(size_t)i*128+64+lane]);
    float mn=fmaxf(m,a), sc=__expf(m-mn), ee=__expf(a-mn);
    s=s*sc+ee; a0=a0*sc+ee*x0; a1=a1*sc+ee*x1; m=mn;
  }
  float inv=1.f/(s+1e-16f);
  P[(size_t)b*128+lane]=a0*inv;
  P[(size_t)b*128+64+lane]=a1*inv;
}

// ==== mol_lin: hb = elu(P @ molW^T + bias), W cached bf16 in LDS ====
__global__ __launch_bounds__(256) void mol_lin_k(const float* __restrict__ P, const float* __restrict__ W,
                         const float* __restrict__ bias, float* __restrict__ hb, int Bn){
  __shared__ bf16 sW[128][132];
  __shared__ float sP[8][128];
  __shared__ float sb[128];
  for (int i=threadIdx.x;i<128*128;i+=256){ int r=i>>7,k=i&127; sW[r][k]=f2b(W[i]); }
  if (threadIdx.x<128) sb[threadIdx.x]=bias[threadIdx.x];
  __syncthreads();
  int sub=threadIdx.x>>5, c0=threadIdx.x&31;
  for (long b0=(long)blockIdx.x*8; b0<Bn; b0+=(long)gridDim.x*8){
    __syncthreads();
    for (int i=threadIdx.x;i<8*32;i+=256){
      int rr=i>>5,q=i&31; long b=b0+rr;
      *(float4*)&sP[rr][q*4] = (b<Bn)? *(const float4*)(P+b*128+q*4) : make_float4(0,0,0,0);
    }
    __syncthreads();
    long b=b0+sub;
    if (b<Bn){
      float acc[4]={0,0,0,0};
      #pragma unroll 4
      for (int k=0;k<128;k++){
        float pv=sP[sub][k];
        #pragma unroll
        for (int j=0;j<4;j++) acc[j]+=pv*b2f(sW[c0+32*j][k]);
      }
      #pragma unroll
      for (int j=0;j<4;j++) hb[b*128+c0+32*j]=elu_f(acc[j]+sb[c0+32*j]);
    }
  }
}

// ---------------- final head (folded: y = out @ (Wh@W2)^T + (b2.Wh+bh)) ----
__global__ void fold_head_k(const float* __restrict__ W2, const float* __restrict__ b2,
                            const float* __restrict__ Wh, const float* __restrict__ bh,
                            float* __restrict__ v){
  __shared__ float sred[128];
  int k=threadIdx.x;
  float a=0.f;
  for (int c=0;c<128;c++) a+=Wh[c]*W2[(size_t)c*128+k];
  v[k]=a;
  sred[k]=b2[k]*Wh[k]; __syncthreads();
  for (int o=64;o;o>>=1){ if (k<o) sred[k]+=sred[k+o]; __syncthreads(); }
  if (k==0) v[128]=sred[0]+bh[0];
}

__global__ void head_dot_k(const float* __restrict__ out, const float* __restrict__ v,
                           float* __restrict__ y, int M){
  __shared__ float sv[129];
  if (threadIdx.x<129) sv[threadIdx.x]=v[threadIdx.x];
  __syncthreads();
  int wv=threadIdx.x>>6, lane=threadIdx.x&63;
  long row=(long)blockIdx.x*4+wv;
  if (row>=M) return;
  float a=out[row*128+lane]*sv[lane]+out[row*128+64+lane]*sv[64+lane];
  #pragma unroll
  for (int o=32;o;o>>=1) a+=__shfl_xor(a,o);
  if (!lane) y[row]=a+sv[128];
}

// ---------------- CSR build ----------------
__global__ void zero_i32_k(int* p, int n){ int i=blockIdx.x*256+threadIdx.x; if (i<n) p[i]=0; }
__global__ void hist_k(const int* __restrict__ dst, int* __restrict__ deg, int n){
  int e=blockIdx.x*256+threadIdx.x; if (e<n) atomicAdd(&deg[dst[e]],1);
}
__global__ void scan1_k(const int* __restrict__ deg, int* __restrict__ ptr,
                        int* __restrict__ part, int n){
  __shared__ int sd[256];
  int base=blockIdx.x*1024, tid=threadIdx.x;
  int v[4]; int ssum=0;
  #pragma unroll
  for (int j=0;j<4;j++){ int idx=base+tid*4+j; v[j]= idx<n? deg[idx]:0; ssum+=v[j]; }
  sd[tid]=ssum; __syncthreads();
  for (int o=1;o<256;o<<=1){ int t = tid>=o? sd[tid-o]:0; __syncthreads(); sd[tid]+=t; __syncthreads(); }
  int excl=sd[tid]-ssum;
  #pragma unroll
  for (int j=0;j<4;j++){ int idx=base+tid*4+j; if (idx<n) ptr[idx]=excl; excl+=v[j]; }
  if (tid==255) part[blockIdx.x]=sd[255];
}
__global__ void scan2_k(int* part, int nb){
  __shared__ int sd[512];
  int tid=threadIdx.x;
  int v= tid<nb? part[tid]:0; sd[tid]=v; __syncthreads();
  for (int o=1;o<512;o<<=1){ int t = tid>=o? sd[tid-o]:0; __syncthreads(); sd[tid]+=t; __syncthreads(); }
  if (tid<nb) part[tid]=sd[tid]-v;
}
__global__ void scan3_k(int* __restrict__ ptr, const int* __restrict__ part,
                        int* __restrict__ wofs, int n, int total){
  int i=blockIdx.x*256+threadIdx.x;
  if (i<n){ int val=ptr[i]+part[i>>10]; ptr[i]=val; wofs[i]=val; }
  if (i==0) ptr[n]=total;
}
__global__ void fill_csr_k(const int* __restrict__ dst, const int* __restrict__ src,
                           int* __restrict__ wofs, int* __restrict__ srcp,
                           int* __restrict__ epos, int n){
  int e=blockIdx.x*256+threadIdx.x;
  if (e<n){ int p=atomicAdd(&wofs[dst[e]],1); srcp[p]=src[e]; epos[e]=p; }
}

// =====================================================================
extern "C" void kernel_launch(void* const* d_in, const int* in_sizes, int n_in,
                              void* d_out, int out_size, void* d_ws, size_t ws_size,
                              hipStream_t stream){
  (void)in_sizes; (void)n_in; (void)out_size; (void)ws_size;
  const float* x0        =(const float*)d_in[0];
  const float* edge_attr =(const float*)d_in[1];
  const float* W_lin1    =(const float*)d_in[2];
  const float* b_lin1    =(const float*)d_in[3];
  const float* gate_W1   =(const float*)d_in[4];
  const float* gate_W2   =(const float*)d_in[5];
  const float* gate_att_l=(const float*)d_in[6];
  const float* gate_att_r=(const float*)d_in[7];
  const float* gate_bias =(const float*)d_in[8];
  const float* g1_Wih=(const float*)d_in[9];  const float* g1_Whh=(const float*)d_in[10];
  const float* g1_bih=(const float*)d_in[11]; const float* g1_bhh=(const float*)d_in[12];
  const float* conv_W=(const float*)d_in[13];
  const float* conv_att_src=(const float*)d_in[14];
  const float* conv_att_dst=(const float*)d_in[15];
  const float* conv_bias   =(const float*)d_in[16];
  const float* g2_Wih=(const float*)d_in[17]; const float* g2_Whh=(const float*)d_in[18];
  const float* g2_bih=(const float*)d_in[19]; const float* g2_bhh=(const float*)d_in[20];
  const float* mol_W=(const float*)d_in[21];
  const float* mol_att_src=(const float*)d_in[22];
  const float* mol_att_dst=(const float*)d_in[23];
  const float* mol_bias   =(const float*)d_in[24];
  const float* gm_Wih=(const float*)d_in[25]; const float* gm_Whh=(const float*)d_in[26];
  const float* gm_bih=(const float*)d_in[27]; const float* gm_bhh=(const float*)d_in[28];
  const float* W_lin2=(const float*)d_in[29]; const float* b_lin2=(const float*)d_in[30];
  const float* W_head=(const float*)d_in[31]; const float* b_head=(const float*)d_in[32];
  const int* ei   =(const int*)d_in[33];
  const int* batch=(const int*)d_in[34];
  const int* src=ei; const int* dst=ei+E_;
  float* y=(float*)d_out;

  // ---- workspace layout (unchanged footprint) ----
  const size_t NH=(size_t)N_*H_, BH=(size_t)B_*H_;
  bf16* b0  =(bf16*)d_ws;           // N*H bf16
  bf16* b1  =b0+NH;                 // N*H bf16
  bf16* b2v =b1+NH;                 // N*H bf16
  float* outA=(float*)(b2v+NH);     // B*H fp32
  float* outB=outA+BH;              // B*H fp32 (also reused as P per-timestep)
  float* hb  =outB+BH;              // B*H fp32
  float* elog=hb+BH;                // E
  float* dsrc=elog+E_;              // N
  float* ddst=dsrc+N_;              // N
  float* alog=ddst+N_;              // N (unused)
  float* wdd =alog+N_;              // 128
  float* dd  =wdd+128;              // B floats (reused: w1c/w2c/wms)
  int* deg =(int*)(dd+B_);          // N
  int* ptr =deg+N_;                 // N+1
  int* wofs=ptr+N_+1;               // N
  int* part=wofs+N_;                // 512
  int* mptr=part+512;               // B+1
  int* srcp=mptr+B_+1;              // E
  int* epos=srcp+E_;                // E
  uintptr_t wbase=((uintptr_t)(epos+E_)+255)&~(uintptr_t)255;
  bf16* wb_gw1 =(bf16*)wbase;        // 128*128
  bf16* wb_gw2 =wb_gw1 +128*128;
  bf16* wb_conv=wb_gw2 +128*128;
  bf16* wb_mol =wb_conv+128*128;     // (unused now, kept for layout stability)
  bf16* wb_g1i =wb_mol +128*128;     // 384*128
  bf16* wb_g1h =wb_g1i +384*128;
  bf16* wb_g2i =wb_g1h +384*128;
  bf16* wb_g2h =wb_g2i +384*128;
  bf16* wb_l1  =wb_g2h +384*128;     // 128*64 (lin1, K padded 39->64)
  float* w1c = dd;                   // convW^T att_src
  float* w2c = dd+128;               // convW^T att_dst
  float* wms = dd+256;               // molW^T att_src

  // ---- weight conversions (one dispatch, 9 segments) ----
  W2B9 wp;
  wp.seg[0]={gate_W1,wb_gw1,128,138,128,128};
  wp.seg[1]={gate_W2,wb_gw2,128,128,128,128};
  wp.seg[2]={conv_W ,wb_conv,128,128,128,128};
  wp.seg[3]={mol_W  ,wb_mol ,128,128,128,128};
  wp.seg[4]={g1_Wih,wb_g1i,384,128,128,128};
  wp.seg[5]={g1_Whh,wb_g1h,384,128,128,128};
  wp.seg[6]={g2_Wih,wb_g2i,384,128,128,128};
  wp.seg[7]={g2_Whh,wb_g2h,384,128,128,128};
  wp.seg[8]={W_lin1,wb_l1 ,128, 39, 64, 39};
  w2ball_k<<<dim3(192,9),256,0,stream>>>(wp);
  fold4_k<<<4,128,0,stream>>>(conv_W,conv_att_src,conv_att_dst,mol_W,mol_att_src,mol_att_dst,
                              w1c,w2c,wms,wdd);

  // ---- CSR by dst (srcp + epos) + molecule ranges ----
  zero_i32_k<<<(N_+255)/256,256,0,stream>>>(deg,N_);
  hist_k<<<(E_+255)/256,256,0,stream>>>(dst,deg,E_);
  int nb=(N_+1023)/1024;
  scan1_k<<<nb,256,0,stream>>>(deg,ptr,part,N_);
  scan2_k<<<1,512,0,stream>>>(part,nb);
  scan3_k<<<(N_+255)/256,256,0,stream>>>(ptr,part,wofs,N_,E_);
  fill_csr_k<<<(E_+255)/256,256,0,stream>>>(dst,src,wofs,srcp,epos,E_);
  mol_ptr_k<<<(B_+1+255)/256,256,0,stream>>>(batch,mptr,N_,B_);

  // ---- lin1: X -> b0 (MFMA) with fused ddst = b0 . att_r ----
  lin1_mfma_k<<<1024,256,0,stream>>>(x0,wb_l1,b_lin1,gate_att_r,b0,ddst,N_);

  const int GL=768, GN8=(N_+31)/32, GN4=(N_+3)/4;
  // ---- GATEConv ----
  lin_mfma_k<0><<<GL,256,0,stream>>>(b0,wb_gw1,nullptr,b1,N_);              // u -> b1
  gate_edge_logits_k<<<8192,256,0,stream>>>(b1,edge_attr,gate_W1,gate_att_l,ddst,src,dst,epos,elog,E_);
  node_gather_k<0><<<GN8,256,0,stream>>>(elog,srcp,ptr,b0,nullptr,b2v,N_);  // S -> b2v
  // ---- GRU1 with folded gw2: x = relu(gru(elu(S@gw2^T+b), b0)) -> b2v ----
  gru_gw2_mfma_k<2><<<1024,512,0,stream>>>(b2v,b0,wb_gw2,gate_bias,wb_g1i,wb_g1h,g1_bih,g1_bhh,b2v,N_);
  // ---- atom GATConv on raw x (convW folded through att + into GRU2) ----
  rowdot2_k<<<GN4,256,0,stream>>>(b2v,w1c,w2c,dsrc,ddst,N_);
  conv_gather_raw_k<<<GN8,256,0,stream>>>(dsrc,ddst,ptr,srcp,b2v,b1,N_);    // S -> b1
  // ---- GRU2 with folded convW: x = relu(gru(relu(S@convW^T+b), b2v)) -> b0 ----
  gru_gw2_mfma_k<1><<<1024,512,0,stream>>>(b1,b2v,wb_conv,conv_bias,wb_g2i,wb_g2h,g2_bih,g2_bhh,b0,N_);
  // ---- readout on raw x (molW folded through att + deferred GEMM) ----
  mol_sum_k<<<(B_+3)/4,256,0,stream>>>(b0,mptr,outA,B_);
  rowdot_k<bf16><<<GN4,256,0,stream>>>(b0,wms,dsrc,N_);
  float* out_cur=outA; float* out_nxt=outB;
  dim3 gm(157,4);
  for (int ts=0; ts<2; ts++){
    float* P=out_nxt;  // dead until gru_scalar writes it; mol_lin consumes P first
    mol_fused_raw_k<<<(B_+3)/4,256,0,stream>>>(dsrc,mptr,b0,wdd,out_cur,P,B_);
    mol_lin_k<<<256,256,0,stream>>>(P,mol_W,mol_bias,hb,B_);
    gru_scalar_k<<<gm,256,0,stream>>>(hb,out_cur,gm_Wih,gm_Whh,gm_bih,gm_bhh,out_nxt,B_);
    float* tmp=out_cur; out_cur=out_nxt; out_nxt=tmp;
  }
  // folded lin2+head: y = out @ (Wh@W2)^T + (b2.Wh + bh)
  fold_head_k<<<1,128,0,stream>>>(W_lin2,b_lin2,W_head,b_head,elog);
  head_dot_k<<<(B_+3)/4,256,0,stream>>>(out_cur,elog,y,B_);
}

// Round 8
// 1089.740 us; speedup vs baseline: 1.0060x; 1.0060x over previous
//
#include <hip/hip_runtime.h>
#include <hip/hip_bf16.h>
#include <type_traits>

typedef __hip_bfloat16 bf16;

constexpr int N_  = 250000;
constexpr int E_  = 500000;
constexpr int B_  = 10000;
constexpr int H_  = 128;

typedef short s8v __attribute__((ext_vector_type(8)));   // 8 bf16 in 4 VGPRs
typedef float f4v __attribute__((ext_vector_type(4)));

__device__ __forceinline__ float b2f(bf16 v){ return __bfloat162float(v); }
__device__ __forceinline__ bf16  f2b(float v){ return __float2bfloat16(v); }
__device__ __forceinline__ float lrelu_f(float v){ return v > 0.f ? v : 0.01f*v; }
__device__ __forceinline__ float sigmoid_f(float x){ return __builtin_amdgcn_rcpf(1.f+__expf(-x)); }
__device__ __forceinline__ float tanh_f(float x){ return 1.f - 2.f*__builtin_amdgcn_rcpf(__expf(2.f*x)+1.f); }
__device__ __forceinline__ float elu_f(float v){ return v > 0.f ? v : __expf(v)-1.f; }
__device__ __forceinline__ unsigned f2b_bits(float f){
  bf16 h=__float2bfloat16(f); unsigned short s; __builtin_memcpy(&s,&h,2); return (unsigned)s;
}
__device__ __forceinline__ void unp8(uint4 v, float* o){
  o[0]=__uint_as_float(v.x<<16); o[1]=__uint_as_float(v.x&0xffff0000u);
  o[2]=__uint_as_float(v.y<<16); o[3]=__uint_as_float(v.y&0xffff0000u);
  o[4]=__uint_as_float(v.z<<16); o[5]=__uint_as_float(v.z&0xffff0000u);
  o[6]=__uint_as_float(v.w<<16); o[7]=__uint_as_float(v.w&0xffff0000u);
}

// ---------------- consolidated fp32->bf16 weight copies (9 segments) -------
struct W2B { const float* s; bf16* d; int rows, ld, ow, cw; };
struct W2B9 { W2B seg[9]; };
__global__ void w2ball_k(W2B9 p){
  W2B g=p.seg[blockIdx.y];
  int i=blockIdx.x*256+threadIdx.x;
  if (i>=g.rows*g.ow) return;
  int r=i/g.ow, k=i-r*g.ow;
  g.d[i] = f2b(k<g.cw ? g.s[(size_t)r*g.ld+k] : 0.f);
}

// ------- lin1+gw1 fused: X[N,39] -> x=lrelu(X@W1^T+b) -> b0;  u = x@gw1^T -> b1;
// ------- fused row-dot ddst = x . att_r ----
__global__ __launch_bounds__(256) void lin1_gw1_k(const float* __restrict__ X0, const bf16* __restrict__ Wb,
                            const float* __restrict__ bias, const float* __restrict__ dvec,
                            const bf16* __restrict__ Wg,
                            bf16* __restrict__ Y, bf16* __restrict__ U,
                            float* __restrict__ dout, int M){
  __shared__ __align__(16) bf16 sx[64][72];
  __shared__ __align__(16) bf16 sy[64][136];
  __shared__ float sdot[4][64];
  int wv=threadIdx.x>>6, lane=threadIdx.x&63;
  int n=lane&15, q=lane>>4;
  int c0=wv*32;
  s8v wB[2][2];
  #pragma unroll
  for (int ct=0;ct<2;ct++)
    #pragma unroll
    for (int kk=0;kk<2;kk++)
      wB[ct][kk]=*(const s8v*)(Wb+(size_t)(c0+ct*16+n)*64+kk*32+q*8);
  s8v wG[2][4];
  #pragma unroll
  for (int ct=0;ct<2;ct++)
    #pragma unroll
    for (int kk=0;kk<4;kk++)
      wG[ct][kk]=*(const s8v*)(Wg+(size_t)(c0+ct*16+n)*128+kk*32+q*8);
  float bb[2];
  #pragma unroll
  for (int ct=0;ct<2;ct++) bb[ct]=bias[c0+ct*16+n];
  float va[2]={dvec[c0+n], dvec[c0+16+n]};
  for (int i=threadIdx.x;i<64*25;i+=256){ int r=i/25,k=39+(i-(i/25)*25); sx[r][k]=f2b(0.f); }
  for (long r0=(long)blockIdx.x*64; r0<M; r0+=(long)gridDim.x*64){
    __syncthreads();
    for (int f=threadIdx.x; f<64*39; f+=256){
      int r=f/39, k=f-(f/39)*39; long row=r0+r;
      sx[r][k]= f2b(row<M ? X0[row*39+k] : 0.f);
    }
    __syncthreads();
    s8v a[4][2];
    #pragma unroll
    for (int rt=0;rt<4;rt++)
      #pragma unroll
      for (int kk=0;kk<2;kk++)
        a[rt][kk]=*(const s8v*)&sx[rt*16+n][kk*32+q*8];
    f4v acc[4][2];
    #pragma unroll
    for (int rt=0;rt<4;rt++)
      #pragma unroll
      for (int ct=0;ct<2;ct++) acc[rt][ct]=(f4v){0.f,0.f,0.f,0.f};
    #pragma unroll
    for (int kk=0;kk<2;kk++)
      #pragma unroll
      for (int rt=0;rt<4;rt++)
        #pragma unroll
        for (int ct=0;ct<2;ct++)
          acc[rt][ct]=__builtin_amdgcn_mfma_f32_16x16x32_bf16(a[rt][kk],wB[ct][kk],acc[rt][ct],0,0,0);
    #pragma unroll
    for (int rt=0;rt<4;rt++){
      #pragma unroll
      for (int rg=0;rg<4;rg++){
        float y0=lrelu_f(acc[rt][0][rg]+bb[0]);
        float y1=lrelu_f(acc[rt][1][rg]+bb[1]);
        int lr=rt*16+q*4+rg;
        long row=r0+lr;
        bf16 h0=f2b(y0), h1=f2b(y1);
        sy[lr][c0+n]   =h0;
        sy[lr][c0+16+n]=h1;
        if (row<M){
          Y[row*128+c0+n]   =h0;
          Y[row*128+c0+16+n]=h1;
        }
        float pa=y0*va[0]+y1*va[1];
        #pragma unroll
        for (int o=1;o<16;o<<=1) pa+=__shfl_xor(pa,o);
        if (n==0) sdot[wv][lr]=pa;
      }
    }
    __syncthreads();
    if (threadIdx.x<64){
      long row=r0+threadIdx.x;
      if (row<M) dout[row]=sdot[0][threadIdx.x]+sdot[1][threadIdx.x]+sdot[2][threadIdx.x]+sdot[3][threadIdx.x];
    }
    // ---- phase 2: u = y @ gw1^T for this wave's 32 cols ----
    f4v acc2[4][2];
    #pragma unroll
    for (int rt=0;rt<4;rt++)
      #pragma unroll
      for (int ct=0;ct<2;ct++) acc2[rt][ct]=(f4v){0.f,0.f,0.f,0.f};
    #pragma unroll
    for (int kk=0;kk<4;kk++){
      s8v a2[4];
      #pragma unroll
      for (int rt=0;rt<4;rt++) a2[rt]=*(const s8v*)&sy[rt*16+n][kk*32+q*8];
      #pragma unroll
      for (int rt=0;rt<4;rt++)
        #pragma unroll
        for (int ct=0;ct<2;ct++)
          acc2[rt][ct]=__builtin_amdgcn_mfma_f32_16x16x32_bf16(a2[rt],wG[ct][kk],acc2[rt][ct],0,0,0);
    }
    #pragma unroll
    for (int ct=0;ct<2;ct++){
      int col=c0+ct*16+n;
      #pragma unroll
      for (int rt=0;rt<4;rt++){
        #pragma unroll
        for (int rg=0;rg<4;rg++){
          long row=r0+rt*16+q*4+rg;
          if (row<M) U[row*128+col]=f2b(acc2[rt][ct][rg]);
        }
      }
    }
  }
}

// ---- MFMA linear, weights in registers, optional fused row-dot(s) ----
template<int ACT,int NDOT>   // ACT: 0 none, 2 elu ; NDOT: 0/1/2 fused dots
__global__ __launch_bounds__(256) void lin_mfma_k(const bf16* __restrict__ X, const bf16* __restrict__ Wb,
                            const float* __restrict__ bias, bf16* __restrict__ Y,
                            const float* __restrict__ v1, const float* __restrict__ v2,
                            float* __restrict__ d1, float* __restrict__ d2, int M){
  __shared__ float sdot[2][4][64];
  int wv=threadIdx.x>>6, lane=threadIdx.x&63;
  int n=lane&15, q=lane>>4;
  int c0=wv*32;
  s8v wB[2][4];
  #pragma unroll
  for (int ct=0;ct<2;ct++)
    #pragma unroll
    for (int kk=0;kk<4;kk++)
      wB[ct][kk]=*(const s8v*)(Wb+(size_t)(c0+ct*16+n)*128+kk*32+q*8);
  float bb[2];
  #pragma unroll
  for (int ct=0;ct<2;ct++) bb[ct]=bias? bias[c0+ct*16+n]:0.f;
  float va[2][2];
  if constexpr (NDOT>=1){ va[0][0]=v1[c0+n]; va[0][1]=v1[c0+16+n]; }
  if constexpr (NDOT>=2){ va[1][0]=v2[c0+n]; va[1][1]=v2[c0+16+n]; }
  for (long r0=(long)blockIdx.x*64; r0<M; r0+=(long)gridDim.x*64){
    s8v a[4][4];
    #pragma unroll
    for (int rt=0;rt<4;rt++){
      long row=r0+rt*16+n; if (row>=M) row=M-1;
      #pragma unroll
      for (int kk=0;kk<4;kk++) a[rt][kk]=*(const s8v*)(X+row*128+kk*32+q*8);
    }
    f4v acc[4][2];
    #pragma unroll
    for (int rt=0;rt<4;rt++)
      #pragma unroll
      for (int ct=0;ct<2;ct++) acc[rt][ct]=(f4v){0.f,0.f,0.f,0.f};
    #pragma unroll
    for (int kk=0;kk<4;kk++)
      #pragma unroll
      for (int rt=0;rt<4;rt++)
        #pragma unroll
        for (int ct=0;ct<2;ct++)
          acc[rt][ct]=__builtin_amdgcn_mfma_f32_16x16x32_bf16(a[rt][kk],wB[ct][kk],acc[rt][ct],0,0,0);
    #pragma unroll
    for (int rt=0;rt<4;rt++){
      #pragma unroll
      for (int rg=0;rg<4;rg++){
        float y0=acc[rt][0][rg]+bb[0];
        float y1=acc[rt][1][rg]+bb[1];
        if (ACT==2){ y0=elu_f(y0); y1=elu_f(y1); }
        long row=r0+rt*16+q*4+rg;
        if (row<M){
          Y[row*128+c0+n]   =f2b(y0);
          Y[row*128+c0+16+n]=f2b(y1);
        }
        if constexpr (NDOT>=1){
          float pa=y0*va[0][0]+y1*va[0][1];
          float pb=0.f;
          if constexpr (NDOT>=2) pb=y0*va[1][0]+y1*va[1][1];
          #pragma unroll
          for (int o=1;o<16;o<<=1){
            pa+=__shfl_xor(pa,o);
            if constexpr (NDOT>=2) pb+=__shfl_xor(pb,o);
          }
          if (n==0){
            sdot[0][wv][rt*16+q*4+rg]=pa;
            if constexpr (NDOT>=2) sdot[1][wv][rt*16+q*4+rg]=pb;
          }
        }
      }
    }
    if constexpr (NDOT>=1){
      __syncthreads();
      if (threadIdx.x<64){
        long row=r0+threadIdx.x;
        if (row<M){
          d1[row]=sdot[0][0][threadIdx.x]+sdot[0][1][threadIdx.x]+sdot[0][2][threadIdx.x]+sdot[0][3][threadIdx.x];
          if constexpr (NDOT>=2)
            d2[row]=sdot[1][0][threadIdx.x]+sdot[1][1][threadIdx.x]+sdot[1][2][threadIdx.x]+sdot[1][3][threadIdx.x];
        }
      }
      __syncthreads();
    }
  }
}

// ---- MFMA fused GRU (atoms): LDS-staged tiles, double-buffered, 512 thr ----
__global__ __launch_bounds__(512,1) void gru_mfma_k(const bf16* __restrict__ A, const bf16* __restrict__ X,
                            const bf16* __restrict__ Wih, const bf16* __restrict__ Whh,
                            const float* __restrict__ bih, const float* __restrict__ bhh,
                            bf16* __restrict__ dest, int M){
  __shared__ __align__(16) bf16 sA[2][32][136];
  __shared__ __align__(16) bf16 sX[2][32][136];
  int wv=threadIdx.x>>6, lane=threadIdx.x&63;
  int n=lane&15, q=lane>>4;
  int c0=wv*16;
  s8v wI[3][4], wH[3][4];
  #pragma unroll
  for (int g=0;g<3;g++)
    #pragma unroll
    for (int kk=0;kk<4;kk++){
      size_t off=((size_t)(g*128+c0+n))*128+kk*32+q*8;
      wI[g][kk]=*(const s8v*)(Wih+off);
      wH[g][kk]=*(const s8v*)(Whh+off);
    }
  int col=c0+n;
  float br =bih[col]+bhh[col];
  float bz =bih[128+col]+bhh[128+col];
  float bni=bih[256+col], bnh=bhh[256+col];

  int srow=wv*4+q;
  int schunk=n;
  long step=(long)gridDim.x*32;
  long r0=(long)blockIdx.x*32;
  int buf=0;
  {
    long rowg=r0+srow; if (rowg>=M) rowg=M-1;
    uint4 va=*(const uint4*)(A+rowg*128+schunk*8);
    uint4 vx=*(const uint4*)(X+rowg*128+schunk*8);
    *(uint4*)&sA[0][srow][schunk*8]=va;
    *(uint4*)&sX[0][srow][schunk*8]=vx;
  }
  __syncthreads();
  for (; r0<M; r0+=step){
    long rn=r0+step;
    uint4 va, vx; bool pre = rn<M;
    if (pre){
      long rowg=rn+srow; if (rowg>=M) rowg=M-1;
      va=*(const uint4*)(A+rowg*128+schunk*8);
      vx=*(const uint4*)(X+rowg*128+schunk*8);
    }
    f4v acc[6][2];
    #pragma unroll
    for (int g=0;g<6;g++)
      #pragma unroll
      for (int rt=0;rt<2;rt++) acc[g][rt]=(f4v){0.f,0.f,0.f,0.f};
    #pragma unroll
    for (int kk=0;kk<4;kk++){
      s8v aA[2], aX[2];
      #pragma unroll
      for (int rt=0;rt<2;rt++){
        aA[rt]=*(const s8v*)&sA[buf][rt*16+n][(kk*4+q)*8];
        aX[rt]=*(const s8v*)&sX[buf][rt*16+n][(kk*4+q)*8];
      }
      #pragma unroll
      for (int g=0;g<3;g++)
        #pragma unroll
        for (int rt=0;rt<2;rt++){
          acc[g  ][rt]=__builtin_amdgcn_mfma_f32_16x16x32_bf16(aA[rt],wI[g][kk],acc[g  ][rt],0,0,0);
          acc[3+g][rt]=__builtin_amdgcn_mfma_f32_16x16x32_bf16(aX[rt],wH[g][kk],acc[3+g][rt],0,0,0);
        }
    }
    float xv[2][4];
    #pragma unroll
    for (int rt=0;rt<2;rt++)
      #pragma unroll
      for (int rg=0;rg<4;rg++)
        xv[rt][rg]=b2f(sX[buf][rt*16+q*4+rg][col]);
    #pragma unroll
    for (int rt=0;rt<2;rt++){
      #pragma unroll
      for (int rg=0;rg<4;rg++){
        long row=r0+rt*16+q*4+rg;
        if (row<M){
          float rgate=sigmoid_f(acc[0][rt][rg]+acc[3][rt][rg]+br);
          float zgate=sigmoid_f(acc[1][rt][rg]+acc[4][rt][rg]+bz);
          float nn=tanh_f(acc[2][rt][rg]+bni + rgate*(acc[5][rt][rg]+bnh));
          float o=(1.f-zgate)*nn + zgate*xv[rt][rg];
          dest[row*128+col]=f2b(fmaxf(o,0.f));
        }
      }
    }
    if (pre){
      *(uint4*)&sA[buf^1][srow][schunk*8]=va;
      *(uint4*)&sX[buf^1][srow][schunk*8]=vx;
    }
    __syncthreads();
    buf^=1;
  }
}

// ------- scalar fused GRU (molecules, fp32 state) ----
__global__ __launch_bounds__(256) void gru_scalar_k(const float* __restrict__ A, const float* __restrict__ X,
                            const float* __restrict__ Wih, const float* __restrict__ Whh,
                            const float* __restrict__ bih, const float* __restrict__ bhh,
                            float* __restrict__ dest, int M){
  __shared__ unsigned sW[6][32*66];
  __shared__ float sA[8][132], sX[8][132];
  __shared__ float sbi[3][32], sbh[3][32];
  int c0 = blockIdx.y*32;
  for (int i=threadIdx.x; i<6*32*64; i+=256){
    int m=i>>11, r=i&2047, c=r>>6, k2=r&63;
    const float* base = (m<3)? Wih : Whh;
    int g = (m<3)? m : m-3;
    const float* wp = base + ((size_t)(g*128 + c0 + c))*128 + 2*k2;
    sW[m][c*66 + k2] = f2b_bits(wp[0]) | (f2b_bits(wp[1])<<16);
  }
  if (threadIdx.x < 96){
    int g=threadIdx.x>>5, c=threadIdx.x&31;
    sbi[g][c]=bih[g*128+c0+c]; sbh[g][c]=bhh[g*128+c0+c];
  }
  __syncthreads();
  int sub=threadIdx.x>>5, c=threadIdx.x&31;
  for (long r0=(long)blockIdx.x*8; r0<M; r0+=(long)gridDim.x*8){
    __syncthreads();
    for (int i=threadIdx.x;i<8*16;i+=256){
      int rr=i>>4, q=i&15; long row=r0+rr;
      if (row<M){
        *(float4*)&sA[rr][q*8]   = *(const float4*)(A+row*128+q*8);
        *(float4*)&sA[rr][q*8+4] = *(const float4*)(A+row*128+q*8+4);
        *(float4*)&sX[rr][q*8]   = *(const float4*)(X+row*128+q*8);
        *(float4*)&sX[rr][q*8+4] = *(const float4*)(X+row*128+q*8+4);
      } else {
        float4 z=make_float4(0,0,0,0);
        *(float4*)&sA[rr][q*8]=z; *(float4*)&sA[rr][q*8+4]=z;
        *(float4*)&sX[rr][q*8]=z; *(float4*)&sX[rr][q*8+4]=z;
      }
    }
    __syncthreads();
    long row=r0+sub;
    if (row<M){
      const unsigned* wri=&sW[0][c*66]; const unsigned* wzi=&sW[1][c*66]; const unsigned* wni=&sW[2][c*66];
      const unsigned* wrh=&sW[3][c*66]; const unsigned* wzh=&sW[4][c*66]; const unsigned* wnh=&sW[5][c*66];
      const float2* xa=(const float2*)sA[sub]; const float2* xb=(const float2*)sX[sub];
      float ari=0,azi=0,ani=0,arh=0,azh=0,anh=0;
      #pragma unroll 8
      for (int k2=0;k2<64;k2++){
        float2 av=xa[k2], bv=xb[k2];
        unsigned u;
        u=wri[k2]; ari += av.x*__uint_as_float(u<<16) + av.y*__uint_as_float(u&0xffff0000u);
        u=wzi[k2]; azi += av.x*__uint_as_float(u<<16) + av.y*__uint_as_float(u&0xffff0000u);
        u=wni[k2]; ani += av.x*__uint_as_float(u<<16) + av.y*__uint_as_float(u&0xffff0000u);
        u=wrh[k2]; arh += bv.x*__uint_as_float(u<<16) + bv.y*__uint_as_float(u&0xffff0000u);
        u=wzh[k2]; azh += bv.x*__uint_as_float(u<<16) + bv.y*__uint_as_float(u&0xffff0000u);
        u=wnh[k2]; anh += bv.x*__uint_as_float(u<<16) + bv.y*__uint_as_float(u&0xffff0000u);
      }
      float rg = sigmoid_f(ari+arh+sbi[0][c]+sbh[0][c]);
      float zg = sigmoid_f(azi+azh+sbi[1][c]+sbh[1][c]);
      float nn = tanh_f(ani+sbi[2][c] + rg*(anh+sbh[2][c]));
      float xv = sX[sub][c0+c];
      float o  = (1.f-zg)*nn + zg*xv;
      dest[row*128+c0+c] = fmaxf(o,0.f);
    }
  }
}

// ---- GATE edge logits: 32 lanes/edge, 1-deep prefetch (best measured) ----
__global__ __launch_bounds__(256) void gate_edge_logits_k(const bf16* __restrict__ u, const float* __restrict__ ea,
                                   const float* __restrict__ gW1, const float* __restrict__ att_l,
                                   const float* __restrict__ ddst, const int* __restrict__ src,
                                   const int* __restrict__ dst, const int* __restrict__ epos,
                                   float* __restrict__ elog, int E){
  int wv=threadIdx.x>>6, lane=threadIdx.x&63;
  int t=lane&31;               // 32 lanes per edge, 4 cols each
  float w[10][4];
  #pragma unroll
  for (int k=0;k<10;k++)
    #pragma unroll
    for (int j=0;j<4;j++)
      w[k][j]=gW1[(size_t)(t*4+j)*138 + 128 + k];
  float al[4];
  #pragma unroll
  for (int j=0;j<4;j++) al[j]=att_l[t*4+j];

  long stride=(long)gridDim.x*8;
  long e=(long)blockIdx.x*8 + wv*2 + (lane>>5);
  if (e>=E) return;
  int sj=src[e];
  uint2 uv=*(const uint2*)(u+(size_t)sj*128+t*4);
  const float2* er=(const float2*)(ea+(size_t)e*10);
  float2 c0=er[0],c1=er[1],c2=er[2],c3=er[3],c4=er[4];
  float dv=ddst[dst[e]];
  int ep=epos[e];
  while (true){
    long en=e+stride; bool has=en<E;
    uint2 uvn=make_uint2(0,0);
    float2 d0={0,0},d1={0,0},d2={0,0},d3={0,0},d4={0,0};
    float dvn=0.f; int epn=0;
    if (has){
      int sjn=src[en];
      uvn=*(const uint2*)(u+(size_t)sjn*128+t*4);
      const float2* ern=(const float2*)(ea+(size_t)en*10);
      d0=ern[0];d1=ern[1];d2=ern[2];d3=ern[3];d4=ern[4];
      dvn=ddst[dst[en]];
      epn=epos[en];
    }
    float uf[4];
    uf[0]=__uint_as_float(uv.x<<16); uf[1]=__uint_as_float(uv.x&0xffff0000u);
    uf[2]=__uint_as_float(uv.y<<16); uf[3]=__uint_as_float(uv.y&0xffff0000u);
    float acc=0.f;
    #pragma unroll
    for (int j=0;j<4;j++){
      float v=uf[j];
      v+=c0.x*w[0][j]; v+=c0.y*w[1][j];
      v+=c1.x*w[2][j]; v+=c1.y*w[3][j];
      v+=c2.x*w[4][j]; v+=c2.y*w[5][j];
      v+=c3.x*w[6][j]; v+=c3.y*w[7][j];
      v+=c4.x*w[8][j]; v+=c4.y*w[9][j];
      acc+=lrelu_f(v)*al[j];
    }
    #pragma unroll
    for (int o=16;o;o>>=1) acc+=__shfl_xor(acc,o);
    if (t==0) elog[ep]=lrelu_f(acc+dv);
    if (!has) break;
    e=en; uv=uvn; c0=d0;c1=d1;c2=d2;c3=d3;c4=d4; dv=dvn; ep=epn;
  }
}

// ---- node_gather + gw2 fused: per 32-node tile, gather S (8 lanes/node,
// ---- 8 nodes/wave) into LDS, then h = elu(S@gw2^T + gbias) via MFMA -> Hout
__global__ __launch_bounds__(256) void node_gather_gw2_k(const float* __restrict__ elog, const int* __restrict__ srcp,
                              const int* __restrict__ ptr, const bf16* __restrict__ V,
                              const bf16* __restrict__ Wg, const float* __restrict__ gbias,
                              bf16* __restrict__ Hout, int M){
  __shared__ __align__(16) bf16 sS[32][136];
  int wv=threadIdx.x>>6, lane=threadIdx.x&63;
  int g=lane>>3, t=lane&7;
  int base=blockIdx.x*32;
  int node=base + wv*8 + g;
  // preload gw2 fragments for this wave's 32 output cols
  int n=lane&15, q=lane>>4;
  int c0=wv*32;
  s8v wG[2][4];
  #pragma unroll
  for (int ct=0;ct<2;ct++)
    #pragma unroll
    for (int kk=0;kk<4;kk++)
      wG[ct][kk]=*(const s8v*)(Wg+(size_t)(c0+ct*16+n)*128+kk*32+q*8);
  // ---- gather phase ----
  float ssum=0.f;
  float acc[16]={0,0,0,0,0,0,0,0,0,0,0,0,0,0,0,0};
  if (node<M){
    int p0=ptr[node], p1=ptr[node+1];
    float m=-INFINITY;
    for (int p=p0+t;p<p1;p+=8) m=fmaxf(m,elog[p]);
    #pragma unroll
    for (int o=4;o;o>>=1) m=fmaxf(m,__shfl_xor(m,o));
    if (p0<p1){
      float lg=elog[p0];
      const uint4* vp=(const uint4*)(V+(size_t)srcp[p0]*128+t*16);
      uint4 va=vp[0], vb=vp[1];
      for (int p=p0+1;p<p1;p++){
        float lgn=elog[p];
        const uint4* vpn=(const uint4*)(V+(size_t)srcp[p]*128+t*16);
        uint4 van=vpn[0], vbn=vpn[1];
        float e=__expf(lg-m); ssum+=e;
        float xf[8]; unp8(va,xf);
        #pragma unroll
        for (int j=0;j<8;j++) acc[j]+=e*xf[j];
        unp8(vb,xf);
        #pragma unroll
        for (int j=0;j<8;j++) acc[8+j]+=e*xf[j];
        lg=lgn; va=van; vb=vbn;
      }
      float e=__expf(lg-m); ssum+=e;
      float xf[8]; unp8(va,xf);
      #pragma unroll
      for (int j=0;j<8;j++) acc[j]+=e*xf[j];
      unp8(vb,xf);
      #pragma unroll
      for (int j=0;j<8;j++) acc[8+j]+=e*xf[j];
    }
  }
  float inv=1.f/(ssum+1e-16f);
  #pragma unroll
  for (int j=0;j<16;j++) acc[j]*=inv;
  uint4 o1,o2;
  o1.x=f2b_bits(acc[0])|(f2b_bits(acc[1])<<16);
  o1.y=f2b_bits(acc[2])|(f2b_bits(acc[3])<<16);
  o1.z=f2b_bits(acc[4])|(f2b_bits(acc[5])<<16);
  o1.w=f2b_bits(acc[6])|(f2b_bits(acc[7])<<16);
  o2.x=f2b_bits(acc[8])|(f2b_bits(acc[9])<<16);
  o2.y=f2b_bits(acc[10])|(f2b_bits(acc[11])<<16);
  o2.z=f2b_bits(acc[12])|(f2b_bits(acc[13])<<16);
  o2.w=f2b_bits(acc[14])|(f2b_bits(acc[15])<<16);
  int r=wv*8+g;
  *(uint4*)&sS[r][t*16]  =o1;
  *(uint4*)&sS[r][t*16+8]=o2;
  __syncthreads();
  // ---- GEMM phase: h = elu(S @ gw2^T + gbias) for this wave's 32 cols ----
  f4v acc2[2][2];
  #pragma unroll
  for (int rt=0;rt<2;rt++)
    #pragma unroll
    for (int ct=0;ct<2;ct++) acc2[rt][ct]=(f4v){0.f,0.f,0.f,0.f};
  #pragma unroll
  for (int kk=0;kk<4;kk++){
    s8v aS[2];
    #pragma unroll
    for (int rt=0;rt<2;rt++) aS[rt]=*(const s8v*)&sS[rt*16+n][kk*32+q*8];
    #pragma unroll
    for (int rt=0;rt<2;rt++)
      #pragma unroll
      for (int ct=0;ct<2;ct++)
        acc2[rt][ct]=__builtin_amdgcn_mfma_f32_16x16x32_bf16(aS[rt],wG[ct][kk],acc2[rt][ct],0,0,0);
  }
  #pragma unroll
  for (int ct=0;ct<2;ct++){
    int col=c0+ct*16+n;
    float bcol=gbias[col];
    #pragma unroll
    for (int rt=0;rt<2;rt++){
      #pragma unroll
      for (int rg=0;rg<4;rg++){
        long row=base+rt*16+q*4+rg;
        if (row<M) Hout[row*128+col]=f2b(elu_f(acc2[rt][ct][rg]+bcol));
      }
    }
  }
}

// ---- conv GAT aggregation: 8 lanes/node, 8 nodes/wave, online softmax ----
__global__ __launch_bounds__(256) void conv_gather_k(const float* __restrict__ dsrc, const float* __restrict__ ddst,
    const int* __restrict__ ptr, const int* __restrict__ srcp,
    const bf16* __restrict__ V, const float* __restrict__ bias, bf16* __restrict__ S, int M){
  int wv=threadIdx.x>>6, lane=threadIdx.x&63;
  int g=lane>>3, t=lane&7;
  int node=blockIdx.x*32 + wv*8 + g;
  if (node>=M) return;
  int p0=ptr[node], p1=ptr[node+1];
  float dvn=ddst[node];
  float m=-INFINITY, s=0.f;
  float acc[16]={0,0,0,0,0,0,0,0,0,0,0,0,0,0,0,0};
  if (p0<p1){
    int sj=srcp[p0];
    float ls=dsrc[sj];
    const uint4* vp=(const uint4*)(V+(size_t)sj*128+t*16);
    uint4 va=vp[0], vb=vp[1];
    for (int p=p0+1;p<p1;p++){
      int sjn=srcp[p];
      float lsn=dsrc[sjn];
      const uint4* vpn=(const uint4*)(V+(size_t)sjn*128+t*16);
      uint4 van=vpn[0], vbn=vpn[1];
      float l=lrelu_f(ls+dvn);
      float mn=fmaxf(m,l), sc=__expf(m-mn), ee=__expf(l-mn);
      float xf[8]; unp8(va,xf);
      s=s*sc+ee;
      #pragma unroll
      for (int j=0;j<8;j++) acc[j]=acc[j]*sc+ee*xf[j];
      unp8(vb,xf);
      #pragma unroll
      for (int j=0;j<8;j++) acc[8+j]=acc[8+j]*sc+ee*xf[j];
      m=mn; ls=lsn; va=van; vb=vbn;
    }
    float l=lrelu_f(ls+dvn);
    float mn=fmaxf(m,l), sc=__expf(m-mn), ee=__expf(l-mn);
    float xf[8]; unp8(va,xf);
    s=s*sc+ee;
    #pragma unroll
    for (int j=0;j<8;j++) acc[j]=acc[j]*sc+ee*xf[j];
    unp8(vb,xf);
    #pragma unroll
    for (int j=0;j<8;j++) acc[8+j]=acc[8+j]*sc+ee*xf[j];
  }
  float inv=1.f/(s+1e-16f);
  float r[16];
  #pragma unroll
  for (int j=0;j<16;j++) r[j]=fmaxf(acc[j]*inv+bias[t*16+j],0.f);
  uint4 o1,o2;
  o1.x=f2b_bits(r[0])|(f2b_bits(r[1])<<16);
  o1.y=f2b_bits(r[2])|(f2b_bits(r[3])<<16);
  o1.z=f2b_bits(r[4])|(f2b_bits(r[5])<<16);
  o1.w=f2b_bits(r[6])|(f2b_bits(r[7])<<16);
  o2.x=f2b_bits(r[8])|(f2b_bits(r[9])<<16);
  o2.y=f2b_bits(r[10])|(f2b_bits(r[11])<<16);
  o2.z=f2b_bits(r[12])|(f2b_bits(r[13])<<16);
  o2.w=f2b_bits(r[14])|(f2b_bits(r[15])<<16);
  *(uint4*)(S+(size_t)node*128+t*16)=o1;
  *(uint4*)(S+(size_t)node*128+t*16+8)=o2;
}

// ---------------- molecule kernels ----------------
__global__ void mol_ptr_k(const int* __restrict__ batch, int* __restrict__ mptr, int n, int Bn){
  int b=blockIdx.x*256+threadIdx.x; if (b>Bn) return;
  if (b==Bn){ mptr[Bn]=n; return; }
  int lo=0, hi=n;
  while (lo<hi){ int mid=(lo+hi)>>1; if (batch[mid]<b) lo=mid+1; else hi=mid; }
  mptr[b]=lo;
}

__global__ void mol_sum_k(const bf16* __restrict__ x, const int* __restrict__ mptr,
                          float* __restrict__ out, int Bn){
  int wv=threadIdx.x>>6, lane=threadIdx.x&63;
  int b=blockIdx.x*4+wv; if (b>=Bn) return;
  int p0=mptr[b], p1=mptr[b+1];
  float a0=0.f,a1=0.f;
  for (int i=p0;i<p1;i++){ a0+=b2f(x[(size_t)i*128+lane]); a1+=b2f(x[(size_t)i*128+64+lane]); }
  out[(size_t)b*128+lane]=fmaxf(a0,0.f); out[(size_t)b*128+64+lane]=fmaxf(a1,0.f);
}

__global__ void fold_att_k(const float* __restrict__ W, const float* __restrict__ att,
                           float* __restrict__ wdd){
  int k=threadIdx.x; float a=0.f;
  for (int c=0;c<128;c++) a+=att[c]*W[(size_t)c*128+k];
  wdd[k]=a;
}

// ==== mol fused: dd=out[b].wdd inline; online softmax over atoms ====
__global__ __launch_bounds__(256) void mol_fused_k(const float* __restrict__ dsrc, const int* __restrict__ mptr,
    const bf16* __restrict__ xs, const float* __restrict__ wdd, const float* __restrict__ outc,
    const float* __restrict__ bias, float* __restrict__ hb, int Bn){
  int wv=threadIdx.x>>6, lane=threadIdx.x&63;
  long b=(long)blockIdx.x*4+wv; if (b>=Bn) return;
  int p0=mptr[b], p1=mptr[b+1];
  float dd=outc[(size_t)b*128+lane]*wdd[lane]+outc[(size_t)b*128+64+lane]*wdd[64+lane];
  #pragma unroll
  for (int o=32;o;o>>=1) dd+=__shfl_xor(dd,o);
  float m=-INFINITY, s=0.f, a0=0.f, a1=0.f;
  for (int i=p0;i<p1;i++){
    float a=lrelu_f(dsrc[i]+dd);
    float x0=b2f(xs[(size_t)i*128+lane]), x1=b2f(xs[(size_t)i*128+64+lane]);
    float mn=fmaxf(m,a), sc=__expf(m-mn), ee=__expf(a-mn);
    s=s*sc+ee; a0=a0*sc+ee*x0; a1=a1*sc+ee*x1; m=mn;
  }
  float inv=1.f/(s+1e-16f);
  hb[(size_t)b*128+lane]=elu_f(a0*inv+bias[lane]);
  hb[(size_t)b*128+64+lane]=elu_f(a1*inv+bias[64+lane]);
}

// ---------------- final head (folded: y = out @ (Wh@W2)^T + (b2.Wh+bh)) ----
__global__ void fold_head_k(const float* __restrict__ W2, const float* __restrict__ b2,
                            const float* __restrict__ Wh, const float* __restrict__ bh,
                            float* __restrict__ v){
  __shared__ float sred[128];
  int k=threadIdx.x;
  float a=0.f;
  for (int c=0;c<128;c++) a+=Wh[c]*W2[(size_t)c*128+k];
  v[k]=a;
  sred[k]=b2[k]*Wh[k]; __syncthreads();
  for (int o=64;o;o>>=1){ if (k<o) sred[k]+=sred[k+o]; __syncthreads(); }
  if (k==0) v[128]=sred[0]+bh[0];
}

__global__ void head_dot_k(const float* __restrict__ out, const float* __restrict__ v,
                           float* __restrict__ y, int M){
  __shared__ float sv[129];
  if (threadIdx.x<129) sv[threadIdx.x]=v[threadIdx.x];
  __syncthreads();
  int wv=threadIdx.x>>6, lane=threadIdx.x&63;
  long row=(long)blockIdx.x*4+wv;
  if (row>=M) return;
  float a=out[row*128+lane]*sv[lane]+out[row*128+64+lane]*sv[64+lane];
  #pragma unroll
  for (int o=32;o;o>>=1) a+=__shfl_xor(a,o);
  if (!lane) y[row]=a+sv[128];
}

// ---------------- CSR build ----------------
__global__ void zero_i32_k(int* p, int n){ int i=blockIdx.x*256+threadIdx.x; if (i<n) p[i]=0; }
__global__ void hist_k(const int* __restrict__ dst, int* __restrict__ deg, int n){
  int e=blockIdx.x*256+threadIdx.x; if (e<n) atomicAdd(&deg[dst[e]],1);
}
__global__ void scan1_k(const int* __restrict__ deg, int* __restrict__ ptr,
                        int* __restrict__ part, int n){
  __shared__ int sd[256];
  int base=blockIdx.x*1024, tid=threadIdx.x;
  int v[4]; int ssum=0;
  #pragma unroll
  for (int j=0;j<4;j++){ int idx=base+tid*4+j; v[j]= idx<n? deg[idx]:0; ssum+=v[j]; }
  sd[tid]=ssum; __syncthreads();
  for (int o=1;o<256;o<<=1){ int t = tid>=o? sd[tid-o]:0; __syncthreads(); sd[tid]+=t; __syncthreads(); }
  int excl=sd[tid]-ssum;
  #pragma unroll
  for (int j=0;j<4;j++){ int idx=base+tid*4+j; if (idx<n) ptr[idx]=excl; excl+=v[j]; }
  if (tid==255) part[blockIdx.x]=sd[255];
}
__global__ void scan2_k(int* part, int nb){
  __shared__ int sd[512];
  int tid=threadIdx.x;
  int v= tid<nb? part[tid]:0; sd[tid]=v; __syncthreads();
  for (int o=1;o<512;o<<=1){ int t = tid>=o? sd[tid-o]:0; __syncthreads(); sd[tid]+=t; __syncthreads(); }
  if (tid<nb) part[tid]=sd[tid]-v;
}
__global__ void scan3_k(int* __restrict__ ptr, const int* __restrict__ part,
                        int* __restrict__ wofs, int n, int total){
  int i=blockIdx.x*256+threadIdx.x;
  if (i<n){ int val=ptr[i]+part[i>>10]; ptr[i]=val; wofs[i]=val; }
  if (i==0) ptr[n]=total;
}
__global__ void fill_csr_k(const int* __restrict__ dst, const int* __restrict__ src,
                           int* __restrict__ wofs, int* __restrict__ srcp,
                           int* __restrict__ epos, int n){
  int e=blockIdx.x*256+threadIdx.x;
  if (e<n){ int p=atomicAdd(&wofs[dst[e]],1); srcp[p]=src[e]; epos[e]=p; }
}

// =====================================================================
extern "C" void kernel_launch(void* const* d_in, const int* in_sizes, int n_in,
                              void* d_out, int out_size, void* d_ws, size_t ws_size,
                              hipStream_t stream){
  (void)in_sizes; (void)n_in; (void)out_size; (void)ws_size;
  const float* x0        =(const float*)d_in[0];
  const float* edge_attr =(const float*)d_in[1];
  const float* W_lin1    =(const float*)d_in[2];
  const float* b_lin1    =(const float*)d_in[3];
  const float* gate_W1   =(const float*)d_in[4];
  const float* gate_W2   =(const float*)d_in[5];
  const float* gate_att_l=(const float*)d_in[6];
  const float* gate_att_r=(const float*)d_in[7];
  const float* gate_bias =(const float*)d_in[8];
  const float* g1_Wih=(const float*)d_in[9];  const float* g1_Whh=(const float*)d_in[10];
  const float* g1_bih=(const float*)d_in[11]; const float* g1_bhh=(const float*)d_in[12];
  const float* conv_W=(const float*)d_in[13];
  const float* conv_att_src=(const float*)d_in[14];
  const float* conv_att_dst=(const float*)d_in[15];
  const float* conv_bias   =(const float*)d_in[16];
  const float* g2_Wih=(const float*)d_in[17]; const float* g2_Whh=(const float*)d_in[18];
  const float* g2_bih=(const float*)d_in[19]; const float* g2_bhh=(const float*)d_in[20];
  const float* mol_W=(const float*)d_in[21];
  const float* mol_att_src=(const float*)d_in[22];
  const float* mol_att_dst=(const float*)d_in[23];
  const float* mol_bias   =(const float*)d_in[24];
  const float* gm_Wih=(const float*)d_in[25]; const float* gm_Whh=(const float*)d_in[26];
  const float* gm_bih=(const float*)d_in[27]; const float* gm_bhh=(const float*)d_in[28];
  const float* W_lin2=(const float*)d_in[29]; const float* b_lin2=(const float*)d_in[30];
  const float* W_head=(const float*)d_in[31]; const float* b_head=(const float*)d_in[32];
  const int* ei   =(const int*)d_in[33];
  const int* batch=(const int*)d_in[34];
  const int* src=ei; const int* dst=ei+E_;
  float* y=(float*)d_out;

  // ---- workspace layout ----
  const size_t NH=(size_t)N_*H_, BH=(size_t)B_*H_;
  bf16* b0  =(bf16*)d_ws;           // N*H bf16
  bf16* b1  =b0+NH;                 // N*H bf16
  bf16* b2v =b1+NH;                 // N*H bf16
  float* outA=(float*)(b2v+NH);     // B*H fp32
  float* outB=outA+BH;
  float* hb  =outB+BH;
  float* elog=hb+BH;                // E
  float* dsrc=elog+E_;              // N
  float* ddst=dsrc+N_;              // N
  float* alog=ddst+N_;              // N (unused)
  float* wdd =alog+N_;              // 128
  float* dd  =wdd+128;              // B (unused)
  int* deg =(int*)(dd+B_);          // N
  int* ptr =deg+N_;                 // N+1
  int* wofs=ptr+N_+1;               // N
  int* part=wofs+N_;                // 512
  int* mptr=part+512;               // B+1
  int* srcp=mptr+B_+1;              // E
  int* epos=srcp+E_;                // E
  uintptr_t wbase=((uintptr_t)(epos+E_)+255)&~(uintptr_t)255;
  bf16* wb_gw1 =(bf16*)wbase;        // 128*128
  bf16* wb_gw2 =wb_gw1 +128*128;
  bf16* wb_conv=wb_gw2 +128*128;
  bf16* wb_mol =wb_conv+128*128;
  bf16* wb_g1i =wb_mol +128*128;     // 384*128
  bf16* wb_g1h =wb_g1i +384*128;
  bf16* wb_g2i =wb_g1h +384*128;
  bf16* wb_g2h =wb_g2i +384*128;
  bf16* wb_l1  =wb_g2h +384*128;     // 128*64 (lin1, K padded 39->64)

  // ---- weight conversions (one dispatch, 9 segments) ----
  W2B9 wp;
  wp.seg[0]={gate_W1,wb_gw1,128,138,128,128};
  wp.seg[1]={gate_W2,wb_gw2,128,128,128,128};
  wp.seg[2]={conv_W ,wb_conv,128,128,128,128};
  wp.seg[3]={mol_W  ,wb_mol ,128,128,128,128};
  wp.seg[4]={g1_Wih,wb_g1i,384,128,128,128};
  wp.seg[5]={g1_Whh,wb_g1h,384,128,128,128};
  wp.seg[6]={g2_Wih,wb_g2i,384,128,128,128};
  wp.seg[7]={g2_Whh,wb_g2h,384,128,128,128};
  wp.seg[8]={W_lin1,wb_l1 ,128, 39, 64, 39};
  w2ball_k<<<dim3(192,9),256,0,stream>>>(wp);

  // ---- CSR by dst (srcp + epos) + molecule ranges ----
  zero_i32_k<<<(N_+255)/256,256,0,stream>>>(deg,N_);
  hist_k<<<(E_+255)/256,256,0,stream>>>(dst,deg,E_);
  int nb=(N_+1023)/1024;
  scan1_k<<<nb,256,0,stream>>>(deg,ptr,part,N_);
  scan2_k<<<1,512,0,stream>>>(part,nb);
  scan3_k<<<(N_+255)/256,256,0,stream>>>(ptr,part,wofs,N_,E_);
  fill_csr_k<<<(E_+255)/256,256,0,stream>>>(dst,src,wofs,srcp,epos,E_);
  mol_ptr_k<<<(B_+1+255)/256,256,0,stream>>>(batch,mptr,N_,B_);

  // ---- lin1 + gw1 fused: x -> b0, u = x@gw1^T -> b1, ddst = x.att_r ----
  lin1_gw1_k<<<1024,256,0,stream>>>(x0,wb_l1,b_lin1,gate_att_r,wb_gw1,b0,b1,ddst,N_);

  const int GL=768, GN32=(N_+31)/32;
  // ---- GATEConv ----
  gate_edge_logits_k<<<8192,256,0,stream>>>(b1,edge_attr,gate_W1,gate_att_l,ddst,src,dst,epos,elog,E_);
  // gather + gw2 GEMM fused: h = elu(S@gw2^T + gate_bias) -> b1 (S never hits HBM)
  node_gather_gw2_k<<<GN32,256,0,stream>>>(elog,srcp,ptr,b0,wb_gw2,gate_bias,b1,N_);
  // ---- GRU1: x=relu(gru(h=b1, x=b0)) -> b2 ----
  gru_mfma_k<<<1024,512,0,stream>>>(b1,b0,wb_g1i,wb_g1h,g1_bih,g1_bhh,b2v,N_);
  // ---- atom GATConv (x lives in b2): xl->b0 with fused dsrc/ddst dots ----
  lin_mfma_k<0,2><<<GL,256,0,stream>>>(b2v,wb_conv,nullptr,b0,conv_att_src,conv_att_dst,dsrc,ddst,N_);
  conv_gather_k<<<GN32,256,0,stream>>>(dsrc,ddst,ptr,srcp,b0,conv_bias,b1,N_); // h -> b1
  // ---- GRU2: x=relu(gru(h=b1, x=b2)) -> b0 ----
  gru_mfma_k<<<1024,512,0,stream>>>(b1,b2v,wb_g2i,wb_g2h,g2_bih,g2_bhh,b0,N_);
  // ---- readout (x lives in b0): xs->b1 with fused dsrc = xs . mol_att_src --
  mol_sum_k<<<(B_+3)/4,256,0,stream>>>(b0,mptr,outA,B_);
  lin_mfma_k<0,1><<<GL,256,0,stream>>>(b0,wb_mol,nullptr,b1,mol_att_src,nullptr,dsrc,nullptr,N_);
  fold_att_k<<<1,128,0,stream>>>(mol_W,mol_att_dst,wdd);
  float* out_cur=outA; float* out_nxt=outB;
  dim3 gm(157,4);
  for (int ts=0; ts<2; ts++){
    mol_fused_k<<<(B_+3)/4,256,0,stream>>>(dsrc,mptr,b1,wdd,out_cur,mol_bias,hb,B_);
    gru_scalar_k<<<gm,256,0,stream>>>(hb,out_cur,gm_Wih,gm_Whh,gm_bih,gm_bhh,out_nxt,B_);
    float* tmp=out_cur; out_cur=out_nxt; out_nxt=tmp;
  }
  // folded lin2+head: y = out @ (Wh@W2)^T + (b2.Wh + bh)
  fold_head_k<<<1,128,0,stream>>>(W_lin2,b_lin2,W_head,b_head,elog);
  head_dot_k<<<(B_+3)/4,256,0,stream>>>(out_cur,elog,y,B_);
}

// Round 9
// 910.060 us; speedup vs baseline: 1.2047x; 1.1974x over previous
//
#include <hip/hip_runtime.h>
#include <hip/hip_bf16.h>
#include <type_traits>

typedef __hip_bfloat16 bf16;

constexpr int N_  = 250000;
constexpr int E_  = 500000;
constexpr int B_  = 10000;
constexpr int H_  = 128;

typedef short s8v __attribute__((ext_vector_type(8)));   // 8 bf16 in 4 VGPRs
typedef float f4v __attribute__((ext_vector_type(4)));

__device__ __forceinline__ float b2f(bf16 v){ return __bfloat162float(v); }
__device__ __forceinline__ bf16  f2b(float v){ return __float2bfloat16(v); }
__device__ __forceinline__ float lrelu_f(float v){ return v > 0.f ? v : 0.01f*v; }
__device__ __forceinline__ float sigmoid_f(float x){ return __builtin_amdgcn_rcpf(1.f+__expf(-x)); }
__device__ __forceinline__ float tanh_f(float x){ return 1.f - 2.f*__builtin_amdgcn_rcpf(__expf(2.f*x)+1.f); }
__device__ __forceinline__ float elu_f(float v){ return v > 0.f ? v : __expf(v)-1.f; }
__device__ __forceinline__ unsigned f2b_bits(float f){
  bf16 h=__float2bfloat16(f); unsigned short s; __builtin_memcpy(&s,&h,2); return (unsigned)s;
}
__device__ __forceinline__ void unp8(uint4 v, float* o){
  o[0]=__uint_as_float(v.x<<16); o[1]=__uint_as_float(v.x&0xffff0000u);
  o[2]=__uint_as_float(v.y<<16); o[3]=__uint_as_float(v.y&0xffff0000u);
  o[4]=__uint_as_float(v.z<<16); o[5]=__uint_as_float(v.z&0xffff0000u);
  o[6]=__uint_as_float(v.w<<16); o[7]=__uint_as_float(v.w&0xffff0000u);
}

// ---------------- consolidated fp32->bf16 weight copies (11 segments) ------
struct W2B { const float* s; bf16* d; int rows, ld, ow, cw; };
struct W2B11 { W2B seg[11]; };
__global__ void w2ball_k(W2B11 p){
  W2B g=p.seg[blockIdx.y];
  int i=blockIdx.x*256+threadIdx.x;
  if (i>=g.rows*g.ow) return;
  int r=i/g.ow, k=i-r*g.ow;
  g.d[i] = f2b(k<g.cw ? g.s[(size_t)r*g.ld+k] : 0.f);
}

// ------- lin1 via MFMA: [N,39] fp32 -> [N,128] bf16, lrelu; fused row-dot --
__global__ __launch_bounds__(256) void lin1_mfma_k(const float* __restrict__ X0, const bf16* __restrict__ Wb,
                            const float* __restrict__ bias, const float* __restrict__ dvec,
                            bf16* __restrict__ Y, float* __restrict__ dout, int M){
  __shared__ __align__(16) bf16 sx[64][72];
  __shared__ float sdot[4][64];
  int wv=threadIdx.x>>6, lane=threadIdx.x&63;
  int n=lane&15, q=lane>>4;
  int c0=wv*32;
  s8v wB[2][2];
  #pragma unroll
  for (int ct=0;ct<2;ct++)
    #pragma unroll
    for (int kk=0;kk<2;kk++)
      wB[ct][kk]=*(const s8v*)(Wb+(size_t)(c0+ct*16+n)*64+kk*32+q*8);
  float bb[2];
  #pragma unroll
  for (int ct=0;ct<2;ct++) bb[ct]=bias[c0+ct*16+n];
  float va[2]={dvec[c0+n], dvec[c0+16+n]};
  for (int i=threadIdx.x;i<64*25;i+=256){ int r=i/25,k=39+(i-(i/25)*25); sx[r][k]=f2b(0.f); }
  for (long r0=(long)blockIdx.x*64; r0<M; r0+=(long)gridDim.x*64){
    __syncthreads();
    for (int f=threadIdx.x; f<64*39; f+=256){
      int r=f/39, k=f-(f/39)*39; long row=r0+r;
      sx[r][k]= f2b(row<M ? X0[row*39+k] : 0.f);
    }
    __syncthreads();
    s8v a[4][2];
    #pragma unroll
    for (int rt=0;rt<4;rt++)
      #pragma unroll
      for (int kk=0;kk<2;kk++)
        a[rt][kk]=*(const s8v*)&sx[rt*16+n][kk*32+q*8];
    f4v acc[4][2];
    #pragma unroll
    for (int rt=0;rt<4;rt++)
      #pragma unroll
      for (int ct=0;ct<2;ct++) acc[rt][ct]=(f4v){0.f,0.f,0.f,0.f};
    #pragma unroll
    for (int kk=0;kk<2;kk++)
      #pragma unroll
      for (int rt=0;rt<4;rt++)
        #pragma unroll
        for (int ct=0;ct<2;ct++)
          acc[rt][ct]=__builtin_amdgcn_mfma_f32_16x16x32_bf16(a[rt][kk],wB[ct][kk],acc[rt][ct],0,0,0);
    #pragma unroll
    for (int rt=0;rt<4;rt++){
      #pragma unroll
      for (int rg=0;rg<4;rg++){
        float y0=lrelu_f(acc[rt][0][rg]+bb[0]);
        float y1=lrelu_f(acc[rt][1][rg]+bb[1]);
        long row=r0+rt*16+q*4+rg;
        if (row<M){
          Y[row*128+c0+n]   =f2b(y0);
          Y[row*128+c0+16+n]=f2b(y1);
        }
        float pa=y0*va[0]+y1*va[1];
        #pragma unroll
        for (int o=1;o<16;o<<=1) pa+=__shfl_xor(pa,o);
        if (n==0) sdot[wv][rt*16+q*4+rg]=pa;
      }
    }
    __syncthreads();
    if (threadIdx.x<64){
      long row=r0+threadIdx.x;
      if (row<M) dout[row]=sdot[0][threadIdx.x]+sdot[1][threadIdx.x]+sdot[2][threadIdx.x]+sdot[3][threadIdx.x];
    }
  }
}

// ---- MFMA linear, weights in registers, optional fused row-dot(s) ----
template<int ACT,int NDOT>   // ACT: 0 none, 2 elu ; NDOT: 0/1/2 fused dots
__global__ __launch_bounds__(256) void lin_mfma_k(const bf16* __restrict__ X, const bf16* __restrict__ Wb,
                            const float* __restrict__ bias, bf16* __restrict__ Y,
                            const float* __restrict__ v1, const float* __restrict__ v2,
                            float* __restrict__ d1, float* __restrict__ d2, int M){
  __shared__ float sdot[2][4][64];
  int wv=threadIdx.x>>6, lane=threadIdx.x&63;
  int n=lane&15, q=lane>>4;
  int c0=wv*32;
  s8v wB[2][4];
  #pragma unroll
  for (int ct=0;ct<2;ct++)
    #pragma unroll
    for (int kk=0;kk<4;kk++)
      wB[ct][kk]=*(const s8v*)(Wb+(size_t)(c0+ct*16+n)*128+kk*32+q*8);
  float bb[2];
  #pragma unroll
  for (int ct=0;ct<2;ct++) bb[ct]=bias? bias[c0+ct*16+n]:0.f;
  float va[2][2];
  if constexpr (NDOT>=1){ va[0][0]=v1[c0+n]; va[0][1]=v1[c0+16+n]; }
  if constexpr (NDOT>=2){ va[1][0]=v2[c0+n]; va[1][1]=v2[c0+16+n]; }
  for (long r0=(long)blockIdx.x*64; r0<M; r0+=(long)gridDim.x*64){
    s8v a[4][4];
    #pragma unroll
    for (int rt=0;rt<4;rt++){
      long row=r0+rt*16+n; if (row>=M) row=M-1;
      #pragma unroll
      for (int kk=0;kk<4;kk++) a[rt][kk]=*(const s8v*)(X+row*128+kk*32+q*8);
    }
    f4v acc[4][2];
    #pragma unroll
    for (int rt=0;rt<4;rt++)
      #pragma unroll
      for (int ct=0;ct<2;ct++) acc[rt][ct]=(f4v){0.f,0.f,0.f,0.f};
    #pragma unroll
    for (int kk=0;kk<4;kk++)
      #pragma unroll
      for (int rt=0;rt<4;rt++)
        #pragma unroll
        for (int ct=0;ct<2;ct++)
          acc[rt][ct]=__builtin_amdgcn_mfma_f32_16x16x32_bf16(a[rt][kk],wB[ct][kk],acc[rt][ct],0,0,0);
    #pragma unroll
    for (int rt=0;rt<4;rt++){
      #pragma unroll
      for (int rg=0;rg<4;rg++){
        float y0=acc[rt][0][rg]+bb[0];
        float y1=acc[rt][1][rg]+bb[1];
        if (ACT==2){ y0=elu_f(y0); y1=elu_f(y1); }
        long row=r0+rt*16+q*4+rg;
        if (row<M){
          Y[row*128+c0+n]   =f2b(y0);
          Y[row*128+c0+16+n]=f2b(y1);
        }
        if constexpr (NDOT>=1){
          float pa=y0*va[0][0]+y1*va[0][1];
          float pb=0.f;
          if constexpr (NDOT>=2) pb=y0*va[1][0]+y1*va[1][1];
          #pragma unroll
          for (int o=1;o<16;o<<=1){
            pa+=__shfl_xor(pa,o);
            if constexpr (NDOT>=2) pb+=__shfl_xor(pb,o);
          }
          if (n==0){
            sdot[0][wv][rt*16+q*4+rg]=pa;
            if constexpr (NDOT>=2) sdot[1][wv][rt*16+q*4+rg]=pb;
          }
        }
      }
    }
    if constexpr (NDOT>=1){
      __syncthreads();
      if (threadIdx.x<64){
        long row=r0+threadIdx.x;
        if (row<M){
          d1[row]=sdot[0][0][threadIdx.x]+sdot[0][1][threadIdx.x]+sdot[0][2][threadIdx.x]+sdot[0][3][threadIdx.x];
          if constexpr (NDOT>=2)
            d2[row]=sdot[1][0][threadIdx.x]+sdot[1][1][threadIdx.x]+sdot[1][2][threadIdx.x]+sdot[1][3][threadIdx.x];
        }
      }
      __syncthreads();
    }
  }
}

// ---- MFMA fused GRU (atoms): LDS-staged tiles, double-buffered, 512 thr ----
__global__ __launch_bounds__(512,1) void gru_mfma_k(const bf16* __restrict__ A, const bf16* __restrict__ X,
                            const bf16* __restrict__ Wih, const bf16* __restrict__ Whh,
                            const float* __restrict__ bih, const float* __restrict__ bhh,
                            bf16* __restrict__ dest, int M){
  __shared__ __align__(16) bf16 sA[2][32][136];
  __shared__ __align__(16) bf16 sX[2][32][136];
  int wv=threadIdx.x>>6, lane=threadIdx.x&63;
  int n=lane&15, q=lane>>4;
  int c0=wv*16;
  s8v wI[3][4], wH[3][4];
  #pragma unroll
  for (int g=0;g<3;g++)
    #pragma unroll
    for (int kk=0;kk<4;kk++){
      size_t off=((size_t)(g*128+c0+n))*128+kk*32+q*8;
      wI[g][kk]=*(const s8v*)(Wih+off);
      wH[g][kk]=*(const s8v*)(Whh+off);
    }
  int col=c0+n;
  float br =bih[col]+bhh[col];
  float bz =bih[128+col]+bhh[128+col];
  float bni=bih[256+col], bnh=bhh[256+col];

  int srow=wv*4+q;
  int schunk=n;
  long step=(long)gridDim.x*32;
  long r0=(long)blockIdx.x*32;
  int buf=0;
  {
    long rowg=r0+srow; if (rowg>=M) rowg=M-1;
    uint4 va=*(const uint4*)(A+rowg*128+schunk*8);
    uint4 vx=*(const uint4*)(X+rowg*128+schunk*8);
    *(uint4*)&sA[0][srow][schunk*8]=va;
    *(uint4*)&sX[0][srow][schunk*8]=vx;
  }
  __syncthreads();
  for (; r0<M; r0+=step){
    long rn=r0+step;
    uint4 va, vx; bool pre = rn<M;
    if (pre){
      long rowg=rn+srow; if (rowg>=M) rowg=M-1;
      va=*(const uint4*)(A+rowg*128+schunk*8);
      vx=*(const uint4*)(X+rowg*128+schunk*8);
    }
    f4v acc[6][2];
    #pragma unroll
    for (int g=0;g<6;g++)
      #pragma unroll
      for (int rt=0;rt<2;rt++) acc[g][rt]=(f4v){0.f,0.f,0.f,0.f};
    #pragma unroll
    for (int kk=0;kk<4;kk++){
      s8v aA[2], aX[2];
      #pragma unroll
      for (int rt=0;rt<2;rt++){
        aA[rt]=*(const s8v*)&sA[buf][rt*16+n][(kk*4+q)*8];
        aX[rt]=*(const s8v*)&sX[buf][rt*16+n][(kk*4+q)*8];
      }
      #pragma unroll
      for (int g=0;g<3;g++)
        #pragma unroll
        for (int rt=0;rt<2;rt++){
          acc[g  ][rt]=__builtin_amdgcn_mfma_f32_16x16x32_bf16(aA[rt],wI[g][kk],acc[g  ][rt],0,0,0);
          acc[3+g][rt]=__builtin_amdgcn_mfma_f32_16x16x32_bf16(aX[rt],wH[g][kk],acc[3+g][rt],0,0,0);
        }
    }
    float xv[2][4];
    #pragma unroll
    for (int rt=0;rt<2;rt++)
      #pragma unroll
      for (int rg=0;rg<4;rg++)
        xv[rt][rg]=b2f(sX[buf][rt*16+q*4+rg][col]);
    #pragma unroll
    for (int rt=0;rt<2;rt++){
      #pragma unroll
      for (int rg=0;rg<4;rg++){
        long row=r0+rt*16+q*4+rg;
        if (row<M){
          float rgate=sigmoid_f(acc[0][rt][rg]+acc[3][rt][rg]+br);
          float zgate=sigmoid_f(acc[1][rt][rg]+acc[4][rt][rg]+bz);
          float nn=tanh_f(acc[2][rt][rg]+bni + rgate*(acc[5][rt][rg]+bnh));
          float o=(1.f-zgate)*nn + zgate*xv[rt][rg];
          dest[row*128+col]=f2b(fmaxf(o,0.f));
        }
      }
    }
    if (pre){
      *(uint4*)&sA[buf^1][srow][schunk*8]=va;
      *(uint4*)&sX[buf^1][srow][schunk*8]=vx;
    }
    __syncthreads();
    buf^=1;
  }
}

// ---- molecule GRU via MFMA: fp32 A/X in, bf16 matmul operands, fp32 state --
// one 32-row tile per block; highway term z*x uses fp32 X from global.
__global__ __launch_bounds__(512,1) void gru_mol_mfma_k(const float* __restrict__ A, const float* __restrict__ X,
                            const bf16* __restrict__ Wih, const bf16* __restrict__ Whh,
                            const float* __restrict__ bih, const float* __restrict__ bhh,
                            float* __restrict__ dest, int M){
  __shared__ __align__(16) bf16 sA[32][136];
  __shared__ __align__(16) bf16 sX[32][136];
  int wv=threadIdx.x>>6, lane=threadIdx.x&63;
  int n=lane&15, q=lane>>4;
  int c0=wv*16;
  s8v wI[3][4], wH[3][4];
  #pragma unroll
  for (int g=0;g<3;g++)
    #pragma unroll
    for (int kk=0;kk<4;kk++){
      size_t off=((size_t)(g*128+c0+n))*128+kk*32+q*8;
      wI[g][kk]=*(const s8v*)(Wih+off);
      wH[g][kk]=*(const s8v*)(Whh+off);
    }
  int col=c0+n;
  float br =bih[col]+bhh[col];
  float bz =bih[128+col]+bhh[128+col];
  float bni=bih[256+col], bnh=bhh[256+col];

  long r0=(long)blockIdx.x*32;
  // ---- stage fp32 -> bf16 LDS (32 rows x 128 cols, 8 elems/thread) ----
  {
    int t=threadIdx.x; int row=t>>4, ch=t&15;
    long rowg=r0+row;
    float4 a1,a2,x1,x2;
    if (rowg<M){
      a1=*(const float4*)(A+rowg*128+ch*8); a2=*(const float4*)(A+rowg*128+ch*8+4);
      x1=*(const float4*)(X+rowg*128+ch*8); x2=*(const float4*)(X+rowg*128+ch*8+4);
    } else {
      a1=a2=x1=x2=make_float4(0,0,0,0);
    }
    uint4 pa, px;
    pa.x=f2b_bits(a1.x)|(f2b_bits(a1.y)<<16); pa.y=f2b_bits(a1.z)|(f2b_bits(a1.w)<<16);
    pa.z=f2b_bits(a2.x)|(f2b_bits(a2.y)<<16); pa.w=f2b_bits(a2.z)|(f2b_bits(a2.w)<<16);
    px.x=f2b_bits(x1.x)|(f2b_bits(x1.y)<<16); px.y=f2b_bits(x1.z)|(f2b_bits(x1.w)<<16);
    px.z=f2b_bits(x2.x)|(f2b_bits(x2.y)<<16); px.w=f2b_bits(x2.z)|(f2b_bits(x2.w)<<16);
    *(uint4*)&sA[row][ch*8]=pa;
    *(uint4*)&sX[row][ch*8]=px;
  }
  __syncthreads();
  f4v acc[6][2];
  #pragma unroll
  for (int g=0;g<6;g++)
    #pragma unroll
    for (int rt=0;rt<2;rt++) acc[g][rt]=(f4v){0.f,0.f,0.f,0.f};
  #pragma unroll
  for (int kk=0;kk<4;kk++){
    s8v aA[2], aX[2];
    #pragma unroll
    for (int rt=0;rt<2;rt++){
      aA[rt]=*(const s8v*)&sA[rt*16+n][(kk*4+q)*8];
      aX[rt]=*(const s8v*)&sX[rt*16+n][(kk*4+q)*8];
    }
    #pragma unroll
    for (int g=0;g<3;g++)
      #pragma unroll
      for (int rt=0;rt<2;rt++){
        acc[g  ][rt]=__builtin_amdgcn_mfma_f32_16x16x32_bf16(aA[rt],wI[g][kk],acc[g  ][rt],0,0,0);
        acc[3+g][rt]=__builtin_amdgcn_mfma_f32_16x16x32_bf16(aX[rt],wH[g][kk],acc[3+g][rt],0,0,0);
      }
  }
  #pragma unroll
  for (int rt=0;rt<2;rt++){
    #pragma unroll
    for (int rg=0;rg<4;rg++){
      long row=r0+rt*16+q*4+rg;
      if (row<M){
        float xv=X[row*128+col];   // fp32 highway term
        float rgate=sigmoid_f(acc[0][rt][rg]+acc[3][rt][rg]+br);
        float zgate=sigmoid_f(acc[1][rt][rg]+acc[4][rt][rg]+bz);
        float nn=tanh_f(acc[2][rt][rg]+bni + rgate*(acc[5][rt][rg]+bnh));
        float o=(1.f-zgate)*nn + zgate*xv;
        dest[row*128+col]=fmaxf(o,0.f);
      }
    }
  }
}

// ---- GATE edge logits: 32 lanes/edge, 1-deep prefetch (best measured) ----
__global__ __launch_bounds__(256) void gate_edge_logits_k(const bf16* __restrict__ u, const float* __restrict__ ea,
                                   const float* __restrict__ gW1, const float* __restrict__ att_l,
                                   const float* __restrict__ ddst, const int* __restrict__ src,
                                   const int* __restrict__ dst, const int* __restrict__ epos,
                                   float* __restrict__ elog, int E){
  int wv=threadIdx.x>>6, lane=threadIdx.x&63;
  int t=lane&31;               // 32 lanes per edge, 4 cols each
  float w[10][4];
  #pragma unroll
  for (int k=0;k<10;k++)
    #pragma unroll
    for (int j=0;j<4;j++)
      w[k][j]=gW1[(size_t)(t*4+j)*138 + 128 + k];
  float al[4];
  #pragma unroll
  for (int j=0;j<4;j++) al[j]=att_l[t*4+j];

  long stride=(long)gridDim.x*8;
  long e=(long)blockIdx.x*8 + wv*2 + (lane>>5);
  if (e>=E) return;
  int sj=src[e];
  uint2 uv=*(const uint2*)(u+(size_t)sj*128+t*4);
  const float2* er=(const float2*)(ea+(size_t)e*10);
  float2 c0=er[0],c1=er[1],c2=er[2],c3=er[3],c4=er[4];
  float dv=ddst[dst[e]];
  int ep=epos[e];
  while (true){
    long en=e+stride; bool has=en<E;
    uint2 uvn=make_uint2(0,0);
    float2 d0={0,0},d1={0,0},d2={0,0},d3={0,0},d4={0,0};
    float dvn=0.f; int epn=0;
    if (has){
      int sjn=src[en];
      uvn=*(const uint2*)(u+(size_t)sjn*128+t*4);
      const float2* ern=(const float2*)(ea+(size_t)en*10);
      d0=ern[0];d1=ern[1];d2=ern[2];d3=ern[3];d4=ern[4];
      dvn=ddst[dst[en]];
      epn=epos[en];
    }
    float uf[4];
    uf[0]=__uint_as_float(uv.x<<16); uf[1]=__uint_as_float(uv.x&0xffff0000u);
    uf[2]=__uint_as_float(uv.y<<16); uf[3]=__uint_as_float(uv.y&0xffff0000u);
    float acc=0.f;
    #pragma unroll
    for (int j=0;j<4;j++){
      float v=uf[j];
      v+=c0.x*w[0][j]; v+=c0.y*w[1][j];
      v+=c1.x*w[2][j]; v+=c1.y*w[3][j];
      v+=c2.x*w[4][j]; v+=c2.y*w[5][j];
      v+=c3.x*w[6][j]; v+=c3.y*w[7][j];
      v+=c4.x*w[8][j]; v+=c4.y*w[9][j];
      acc+=lrelu_f(v)*al[j];
    }
    #pragma unroll
    for (int o=16;o;o>>=1) acc+=__shfl_xor(acc,o);
    if (t==0) elog[ep]=lrelu_f(acc+dv);
    if (!has) break;
    e=en; uv=uvn; c0=d0;c1=d1;c2=d2;c3=d3;c4=d4; dv=dvn; ep=epn;
  }
}

// ------- per-node softmax + weighted sum; 8 lanes/node, 8 nodes/wave -------
template<int ACT>   // 0 none
__global__ void node_gather_k(const float* __restrict__ elog, const int* __restrict__ srcp,
                              const int* __restrict__ ptr, const bf16* __restrict__ V,
                              const float* __restrict__ bias, bf16* __restrict__ S, int M){
  int wv=threadIdx.x>>6, lane=threadIdx.x&63;
  int g=lane>>3, t=lane&7;
  int node=blockIdx.x*32 + wv*8 + g;
  if (node>=M) return;
  int p0=ptr[node], p1=ptr[node+1];
  float m=-INFINITY;
  for (int p=p0+t;p<p1;p+=8) m=fmaxf(m,elog[p]);
  #pragma unroll
  for (int o=4;o;o>>=1) m=fmaxf(m,__shfl_xor(m,o));
  float ssum=0.f;
  float acc[16]={0,0,0,0,0,0,0,0,0,0,0,0,0,0,0,0};
  if (p0<p1){
    float lg=elog[p0];
    const uint4* vp=(const uint4*)(V+(size_t)srcp[p0]*128+t*16);
    uint4 va=vp[0], vb=vp[1];
    for (int p=p0+1;p<p1;p++){
      float lgn=elog[p];
      const uint4* vpn=(const uint4*)(V+(size_t)srcp[p]*128+t*16);
      uint4 van=vpn[0], vbn=vpn[1];
      float e=__expf(lg-m); ssum+=e;
      float xf[8]; unp8(va,xf);
      #pragma unroll
      for (int j=0;j<8;j++) acc[j]+=e*xf[j];
      unp8(vb,xf);
      #pragma unroll
      for (int j=0;j<8;j++) acc[8+j]+=e*xf[j];
      lg=lgn; va=van; vb=vbn;
    }
    float e=__expf(lg-m); ssum+=e;
    float xf[8]; unp8(va,xf);
    #pragma unroll
    for (int j=0;j<8;j++) acc[j]+=e*xf[j];
    unp8(vb,xf);
    #pragma unroll
    for (int j=0;j<8;j++) acc[8+j]+=e*xf[j];
  }
  float inv=1.f/(ssum+1e-16f);
  #pragma unroll
  for (int j=0;j<16;j++) acc[j]*=inv;
  if (ACT==1){
    #pragma unroll
    for (int j=0;j<16;j++) acc[j]=fmaxf(acc[j]+bias[t*16+j],0.f);
  }
  uint4 o1,o2;
  o1.x=f2b_bits(acc[0])|(f2b_bits(acc[1])<<16);
  o1.y=f2b_bits(acc[2])|(f2b_bits(acc[3])<<16);
  o1.z=f2b_bits(acc[4])|(f2b_bits(acc[5])<<16);
  o1.w=f2b_bits(acc[6])|(f2b_bits(acc[7])<<16);
  o2.x=f2b_bits(acc[8])|(f2b_bits(acc[9])<<16);
  o2.y=f2b_bits(acc[10])|(f2b_bits(acc[11])<<16);
  o2.z=f2b_bits(acc[12])|(f2b_bits(acc[13])<<16);
  o2.w=f2b_bits(acc[14])|(f2b_bits(acc[15])<<16);
  *(uint4*)(S+(size_t)node*128+t*16)=o1;
  *(uint4*)(S+(size_t)node*128+t*16+8)=o2;
}

// ---- conv GAT aggregation: 8 lanes/node, 8 nodes/wave, online softmax ----
__global__ __launch_bounds__(256) void conv_gather_k(const float* __restrict__ dsrc, const float* __restrict__ ddst,
    const int* __restrict__ ptr, const int* __restrict__ srcp,
    const bf16* __restrict__ V, const float* __restrict__ bias, bf16* __restrict__ S, int M){
  int wv=threadIdx.x>>6, lane=threadIdx.x&63;
  int g=lane>>3, t=lane&7;
  int node=blockIdx.x*32 + wv*8 + g;
  if (node>=M) return;
  int p0=ptr[node], p1=ptr[node+1];
  float dvn=ddst[node];
  float m=-INFINITY, s=0.f;
  float acc[16]={0,0,0,0,0,0,0,0,0,0,0,0,0,0,0,0};
  if (p0<p1){
    int sj=srcp[p0];
    float ls=dsrc[sj];
    const uint4* vp=(const uint4*)(V+(size_t)sj*128+t*16);
    uint4 va=vp[0], vb=vp[1];
    for (int p=p0+1;p<p1;p++){
      int sjn=srcp[p];
      float lsn=dsrc[sjn];
      const uint4* vpn=(const uint4*)(V+(size_t)sjn*128+t*16);
      uint4 van=vpn[0], vbn=vpn[1];
      float l=lrelu_f(ls+dvn);
      float mn=fmaxf(m,l), sc=__expf(m-mn), ee=__expf(l-mn);
      float xf[8]; unp8(va,xf);
      s=s*sc+ee;
      #pragma unroll
      for (int j=0;j<8;j++) acc[j]=acc[j]*sc+ee*xf[j];
      unp8(vb,xf);
      #pragma unroll
      for (int j=0;j<8;j++) acc[8+j]=acc[8+j]*sc+ee*xf[j];
      m=mn; ls=lsn; va=van; vb=vbn;
    }
    float l=lrelu_f(ls+dvn);
    float mn=fmaxf(m,l), sc=__expf(m-mn), ee=__expf(l-mn);
    float xf[8]; unp8(va,xf);
    s=s*sc+ee;
    #pragma unroll
    for (int j=0;j<8;j++) acc[j]=acc[j]*sc+ee*xf[j];
    unp8(vb,xf);
    #pragma unroll
    for (int j=0;j<8;j++) acc[8+j]=acc[8+j]*sc+ee*xf[j];
  }
  float inv=1.f/(s+1e-16f);
  float r[16];
  #pragma unroll
  for (int j=0;j<16;j++) r[j]=fmaxf(acc[j]*inv+bias[t*16+j],0.f);
  uint4 o1,o2;
  o1.x=f2b_bits(r[0])|(f2b_bits(r[1])<<16);
  o1.y=f2b_bits(r[2])|(f2b_bits(r[3])<<16);
  o1.z=f2b_bits(r[4])|(f2b_bits(r[5])<<16);
  o1.w=f2b_bits(r[6])|(f2b_bits(r[7])<<16);
  o2.x=f2b_bits(r[8])|(f2b_bits(r[9])<<16);
  o2.y=f2b_bits(r[10])|(f2b_bits(r[11])<<16);
  o2.z=f2b_bits(r[12])|(f2b_bits(r[13])<<16);
  o2.w=f2b_bits(r[14])|(f2b_bits(r[15])<<16);
  *(uint4*)(S+(size_t)node*128+t*16)=o1;
  *(uint4*)(S+(size_t)node*128+t*16+8)=o2;
}

// ---------------- molecule kernels ----------------
__global__ void mol_ptr_k(const int* __restrict__ batch, int* __restrict__ mptr, int n, int Bn){
  int b=blockIdx.x*256+threadIdx.x; if (b>Bn) return;
  if (b==Bn){ mptr[Bn]=n; return; }
  int lo=0, hi=n;
  while (lo<hi){ int mid=(lo+hi)>>1; if (batch[mid]<b) lo=mid+1; else hi=mid; }
  mptr[b]=lo;
}

__global__ void mol_sum_k(const bf16* __restrict__ x, const int* __restrict__ mptr,
                          float* __restrict__ out, int Bn){
  int wv=threadIdx.x>>6, lane=threadIdx.x&63;
  int b=blockIdx.x*4+wv; if (b>=Bn) return;
  int p0=mptr[b], p1=mptr[b+1];
  float a0=0.f,a1=0.f;
  for (int i=p0;i<p1;i++){ a0+=b2f(x[(size_t)i*128+lane]); a1+=b2f(x[(size_t)i*128+64+lane]); }
  out[(size_t)b*128+lane]=fmaxf(a0,0.f); out[(size_t)b*128+64+lane]=fmaxf(a1,0.f);
}

__global__ void fold_att_k(const float* __restrict__ W, const float* __restrict__ att,
                           float* __restrict__ wdd){
  int k=threadIdx.x; float a=0.f;
  for (int c=0;c<128;c++) a+=att[c]*W[(size_t)c*128+k];
  wdd[k]=a;
}

// ==== mol fused: dd=out[b].wdd inline; online softmax over atoms ====
__global__ __launch_bounds__(256) void mol_fused_k(const float* __restrict__ dsrc, const int* __restrict__ mptr,
    const bf16* __restrict__ xs, const float* __restrict__ wdd, const float* __restrict__ outc,
    const float* __restrict__ bias, float* __restrict__ hb, int Bn){
  int wv=threadIdx.x>>6, lane=threadIdx.x&63;
  long b=(long)blockIdx.x*4+wv; if (b>=Bn) return;
  int p0=mptr[b], p1=mptr[b+1];
  float dd=outc[(size_t)b*128+lane]*wdd[lane]+outc[(size_t)b*128+64+lane]*wdd[64+lane];
  #pragma unroll
  for (int o=32;o;o>>=1) dd+=__shfl_xor(dd,o);
  float m=-INFINITY, s=0.f, a0=0.f, a1=0.f;
  for (int i=p0;i<p1;i++){
    float a=lrelu_f(dsrc[i]+dd);
    float x0=b2f(xs[(size_t)i*128+lane]), x1=b2f(xs[(size_t)i*128+64+lane]);
    float mn=fmaxf(m,a), sc=__expf(m-mn), ee=__expf(a-mn);
    s=s*sc+ee; a0=a0*sc+ee*x0; a1=a1*sc+ee*x1; m=mn;
  }
  float inv=1.f/(s+1e-16f);
  hb[(size_t)b*128+lane]=elu_f(a0*inv+bias[lane]);
  hb[(size_t)b*128+64+lane]=elu_f(a1*inv+bias[64+lane]);
}

// ---------------- final head (folded: y = out @ (Wh@W2)^T + (b2.Wh+bh)) ----
__global__ void fold_head_k(const float* __restrict__ W2, const float* __restrict__ b2,
                            const float* __restrict__ Wh, const float* __restrict__ bh,
                            float* __restrict__ v){
  __shared__ float sred[128];
  int k=threadIdx.x;
  float a=0.f;
  for (int c=0;c<128;c++) a+=Wh[c]*W2[(size_t)c*128+k];
  v[k]=a;
  sred[k]=b2[k]*Wh[k]; __syncthreads();
  for (int o=64;o;o>>=1){ if (k<o) sred[k]+=sred[k+o]; __syncthreads(); }
  if (k==0) v[128]=sred[0]+bh[0];
}

__global__ void head_dot_k(const float* __restrict__ out, const float* __restrict__ v,
                           float* __restrict__ y, int M){
  __shared__ float sv[129];
  if (threadIdx.x<129) sv[threadIdx.x]=v[threadIdx.x];
  __syncthreads();
  int wv=threadIdx.x>>6, lane=threadIdx.x&63;
  long row=(long)blockIdx.x*4+wv;
  if (row>=M) return;
  float a=out[row*128+lane]*sv[lane]+out[row*128+64+lane]*sv[64+lane];
  #pragma unroll
  for (int o=32;o;o>>=1) a+=__shfl_xor(a,o);
  if (!lane) y[row]=a+sv[128];
}

// ---------------- CSR build ----------------
__global__ void zero_i32_k(int* p, int n){ int i=blockIdx.x*256+threadIdx.x; if (i<n) p[i]=0; }
__global__ void hist_k(const int* __restrict__ dst, int* __restrict__ deg, int n){
  int e=blockIdx.x*256+threadIdx.x; if (e<n) atomicAdd(&deg[dst[e]],1);
}
__global__ void scan1_k(const int* __restrict__ deg, int* __restrict__ ptr,
                        int* __restrict__ part, int n){
  __shared__ int sd[256];
  int base=blockIdx.x*1024, tid=threadIdx.x;
  int v[4]; int ssum=0;
  #pragma unroll
  for (int j=0;j<4;j++){ int idx=base+tid*4+j; v[j]= idx<n? deg[idx]:0; ssum+=v[j]; }
  sd[tid]=ssum; __syncthreads();
  for (int o=1;o<256;o<<=1){ int t = tid>=o? sd[tid-o]:0; __syncthreads(); sd[tid]+=t; __syncthreads(); }
  int excl=sd[tid]-ssum;
  #pragma unroll
  for (int j=0;j<4;j++){ int idx=base+tid*4+j; if (idx<n) ptr[idx]=excl; excl+=v[j]; }
  if (tid==255) part[blockIdx.x]=sd[255];
}
__global__ void scan2_k(int* part, int nb){
  __shared__ int sd[512];
  int tid=threadIdx.x;
  int v= tid<nb? part[tid]:0; sd[tid]=v; __syncthreads();
  for (int o=1;o<512;o<<=1){ int t = tid>=o? sd[tid-o]:0; __syncthreads(); sd[tid]+=t; __syncthreads(); }
  if (tid<nb) part[tid]=sd[tid]-v;
}
__global__ void scan3_k(int* __restrict__ ptr, const int* __restrict__ part,
                        int* __restrict__ wofs, int n, int total){
  int i=blockIdx.x*256+threadIdx.x;
  if (i<n){ int val=ptr[i]+part[i>>10]; ptr[i]=val; wofs[i]=val; }
  if (i==0) ptr[n]=total;
}
__global__ void fill_csr_k(const int* __restrict__ dst, const int* __restrict__ src,
                           int* __restrict__ wofs, int* __restrict__ srcp,
                           int* __restrict__ epos, int n){
  int e=blockIdx.x*256+threadIdx.x;
  if (e<n){ int p=atomicAdd(&wofs[dst[e]],1); srcp[p]=src[e]; epos[e]=p; }
}

// =====================================================================
extern "C" void kernel_launch(void* const* d_in, const int* in_sizes, int n_in,
                              void* d_out, int out_size, void* d_ws, size_t ws_size,
                              hipStream_t stream){
  (void)in_sizes; (void)n_in; (void)out_size; (void)ws_size;
  const float* x0        =(const float*)d_in[0];
  const float* edge_attr =(const float*)d_in[1];
  const float* W_lin1    =(const float*)d_in[2];
  const float* b_lin1    =(const float*)d_in[3];
  const float* gate_W1   =(const float*)d_in[4];
  const float* gate_W2   =(const float*)d_in[5];
  const float* gate_att_l=(const float*)d_in[6];
  const float* gate_att_r=(const float*)d_in[7];
  const float* gate_bias =(const float*)d_in[8];
  const float* g1_Wih=(const float*)d_in[9];  const float* g1_Whh=(const float*)d_in[10];
  const float* g1_bih=(const float*)d_in[11]; const float* g1_bhh=(const float*)d_in[12];
  const float* conv_W=(const float*)d_in[13];
  const float* conv_att_src=(const float*)d_in[14];
  const float* conv_att_dst=(const float*)d_in[15];
  const float* conv_bias   =(const float*)d_in[16];
  const float* g2_Wih=(const float*)d_in[17]; const float* g2_Whh=(const float*)d_in[18];
  const float* g2_bih=(const float*)d_in[19]; const float* g2_bhh=(const float*)d_in[20];
  const float* mol_W=(const float*)d_in[21];
  const float* mol_att_src=(const float*)d_in[22];
  const float* mol_att_dst=(const float*)d_in[23];
  const float* mol_bias   =(const float*)d_in[24];
  const float* gm_Wih=(const float*)d_in[25]; const float* gm_Whh=(const float*)d_in[26];
  const float* gm_bih=(const float*)d_in[27]; const float* gm_bhh=(const float*)d_in[28];
  const float* W_lin2=(const float*)d_in[29]; const float* b_lin2=(const float*)d_in[30];
  const float* W_head=(const float*)d_in[31]; const float* b_head=(const float*)d_in[32];
  const int* ei   =(const int*)d_in[33];
  const int* batch=(const int*)d_in[34];
  const int* src=ei; const int* dst=ei+E_;
  float* y=(float*)d_out;

  // ---- workspace layout ----
  const size_t NH=(size_t)N_*H_, BH=(size_t)B_*H_;
  bf16* b0  =(bf16*)d_ws;           // N*H bf16
  bf16* b1  =b0+NH;                 // N*H bf16
  bf16* b2v =b1+NH;                 // N*H bf16
  float* outA=(float*)(b2v+NH);     // B*H fp32
  float* outB=outA+BH;
  float* hb  =outB+BH;
  float* elog=hb+BH;                // E
  float* dsrc=elog+E_;              // N
  float* ddst=dsrc+N_;              // N
  float* alog=ddst+N_;              // N (unused)
  float* wdd =alog+N_;              // 128
  float* dd  =wdd+128;              // B (unused)
  int* deg =(int*)(dd+B_);          // N
  int* ptr =deg+N_;                 // N+1
  int* wofs=ptr+N_+1;               // N
  int* part=wofs+N_;                // 512
  int* mptr=part+512;               // B+1
  int* srcp=mptr+B_+1;              // E
  int* epos=srcp+E_;                // E
  uintptr_t wbase=((uintptr_t)(epos+E_)+255)&~(uintptr_t)255;
  bf16* wb_gw1 =(bf16*)wbase;        // 128*128
  bf16* wb_gw2 =wb_gw1 +128*128;
  bf16* wb_conv=wb_gw2 +128*128;
  bf16* wb_mol =wb_conv+128*128;
  bf16* wb_g1i =wb_mol +128*128;     // 384*128
  bf16* wb_g1h =wb_g1i +384*128;
  bf16* wb_g2i =wb_g1h +384*128;
  bf16* wb_g2h =wb_g2i +384*128;
  bf16* wb_l1  =wb_g2h +384*128;     // 128*64 (lin1, K padded 39->64)
  bf16* wb_gmi =wb_l1  +128*64;      // 384*128 (molecule GRU)
  bf16* wb_gmh =wb_gmi +384*128;

  // ---- weight conversions (one dispatch, 11 segments) ----
  W2B11 wp;
  wp.seg[0]={gate_W1,wb_gw1,128,138,128,128};
  wp.seg[1]={gate_W2,wb_gw2,128,128,128,128};
  wp.seg[2]={conv_W ,wb_conv,128,128,128,128};
  wp.seg[3]={mol_W  ,wb_mol ,128,128,128,128};
  wp.seg[4]={g1_Wih,wb_g1i,384,128,128,128};
  wp.seg[5]={g1_Whh,wb_g1h,384,128,128,128};
  wp.seg[6]={g2_Wih,wb_g2i,384,128,128,128};
  wp.seg[7]={g2_Whh,wb_g2h,384,128,128,128};
  wp.seg[8]={W_lin1,wb_l1 ,128, 39, 64, 39};
  wp.seg[9]={gm_Wih,wb_gmi,384,128,128,128};
  wp.seg[10]={gm_Whh,wb_gmh,384,128,128,128};
  w2ball_k<<<dim3(192,11),256,0,stream>>>(wp);

  // ---- CSR by dst (srcp + epos) + molecule ranges ----
  zero_i32_k<<<(N_+255)/256,256,0,stream>>>(deg,N_);
  hist_k<<<(E_+255)/256,256,0,stream>>>(dst,deg,E_);
  int nb=(N_+1023)/1024;
  scan1_k<<<nb,256,0,stream>>>(deg,ptr,part,N_);
  scan2_k<<<1,512,0,stream>>>(part,nb);
  scan3_k<<<(N_+255)/256,256,0,stream>>>(ptr,part,wofs,N_,E_);
  fill_csr_k<<<(E_+255)/256,256,0,stream>>>(dst,src,wofs,srcp,epos,E_);
  mol_ptr_k<<<(B_+1+255)/256,256,0,stream>>>(batch,mptr,N_,B_);

  // ---- lin1: X -> b0 (MFMA) with fused ddst = b0 . att_r ----
  lin1_mfma_k<<<1024,256,0,stream>>>(x0,wb_l1,b_lin1,gate_att_r,b0,ddst,N_);

  const int GL=768, GN8=(N_+31)/32;
  // ---- GATEConv ----
  lin_mfma_k<0,0><<<GL,256,0,stream>>>(b0,wb_gw1,nullptr,b1,nullptr,nullptr,nullptr,nullptr,N_); // u -> b1
  gate_edge_logits_k<<<8192,256,0,stream>>>(b1,edge_attr,gate_W1,gate_att_l,ddst,src,dst,epos,elog,E_);
  node_gather_k<0><<<GN8,256,0,stream>>>(elog,srcp,ptr,b0,nullptr,b2v,N_);   // S -> b2
  lin_mfma_k<2,0><<<GL,256,0,stream>>>(b2v,wb_gw2,gate_bias,b1,nullptr,nullptr,nullptr,nullptr,N_); // h=elu -> b1
  // ---- GRU1: x=relu(gru(h=b1, x=b0)) -> b2 ----
  gru_mfma_k<<<1024,512,0,stream>>>(b1,b0,wb_g1i,wb_g1h,g1_bih,g1_bhh,b2v,N_);
  // ---- atom GATConv (x lives in b2): xl->b0 with fused dsrc/ddst dots ----
  lin_mfma_k<0,2><<<GL,256,0,stream>>>(b2v,wb_conv,nullptr,b0,conv_att_src,conv_att_dst,dsrc,ddst,N_);
  conv_gather_k<<<GN8,256,0,stream>>>(dsrc,ddst,ptr,srcp,b0,conv_bias,b1,N_); // h -> b1
  // ---- GRU2: x=relu(gru(h=b1, x=b2)) -> b0 ----
  gru_mfma_k<<<1024,512,0,stream>>>(b1,b2v,wb_g2i,wb_g2h,g2_bih,g2_bhh,b0,N_);
  // ---- readout (x lives in b0): xs->b1 with fused dsrc = xs . mol_att_src --
  mol_sum_k<<<(B_+3)/4,256,0,stream>>>(b0,mptr,outA,B_);
  lin_mfma_k<0,1><<<GL,256,0,stream>>>(b0,wb_mol,nullptr,b1,mol_att_src,nullptr,dsrc,nullptr,N_);
  fold_att_k<<<1,128,0,stream>>>(mol_W,mol_att_dst,wdd);
  float* out_cur=outA; float* out_nxt=outB;
  const int GB32=(B_+31)/32;
  for (int ts=0; ts<2; ts++){
    mol_fused_k<<<(B_+3)/4,256,0,stream>>>(dsrc,mptr,b1,wdd,out_cur,mol_bias,hb,B_);
    gru_mol_mfma_k<<<GB32,512,0,stream>>>(hb,out_cur,wb_gmi,wb_gmh,gm_bih,gm_bhh,out_nxt,B_);
    float* tmp=out_cur; out_cur=out_nxt; out_nxt=tmp;
  }
  // folded lin2+head: y = out @ (Wh@W2)^T + (b2.Wh + bh)
  fold_head_k<<<1,128,0,stream>>>(W_lin2,b_lin2,W_head,b_head,elog);
  head_dot_k<<<(B_+3)/4,256,0,stream>>>(out_cur,elog,y,B_);
}